// Round 3
// baseline (901.211 us; speedup 1.0000x reference)
//
#include <hip/hip_runtime.h>
#include <hip/hip_bf16.h>
#include <math.h>

#define N_NODES 20000
#define N_EDGES 200000
#define XROW    1480   // EMB + MD

typedef __attribute__((ext_vector_type(8))) _Float16 f16x8;
typedef __attribute__((ext_vector_type(8))) unsigned short u16x8;
typedef __attribute__((ext_vector_type(4))) float f32x4v;

// ---------------- reduction helpers ----------------
__device__ __forceinline__ float wsum(float v){
#pragma unroll
  for (int o=32;o>0;o>>=1) v += __shfl_down(v,o);
  return v;
}
__device__ __forceinline__ float wmax(float v){
#pragma unroll
  for (int o=32;o>0;o>>=1) v = fmaxf(v,__shfl_down(v,o));
  return v;
}
// butterfly: result in ALL lanes
__device__ __forceinline__ float wsum_all(float v){
#pragma unroll
  for (int o=32;o>0;o>>=1) v += __shfl_xor(v,o);
  return v;
}
__device__ __forceinline__ float wmax_all(float v){
#pragma unroll
  for (int o=32;o>0;o>>=1) v = fmaxf(v,__shfl_xor(v,o));
  return v;
}

__device__ __forceinline__ unsigned short f2hu(float f){
  _Float16 h = (_Float16)f;
  return __builtin_bit_cast(unsigned short, h);
}
__device__ __forceinline__ float hu2f(unsigned short u){
  return (float)__builtin_bit_cast(_Float16, u);
}

__device__ __forceinline__ void async_copy16(void* lds, const void* g){
  __builtin_amdgcn_global_load_lds((const __attribute__((address_space(1))) void*)g,
                                   (__attribute__((address_space(3))) void*)lds, 16, 0, 0);
}

// ---------------- edge preprocessing (once, reused 3 layers) ----------------
__global__ void edge_count_kernel(const int* __restrict__ ei, const float* __restrict__ ea,
                                  int* __restrict__ cnt, float* __restrict__ easum, int E){
  int e = blockIdx.x*256 + threadIdx.x;
  if (e >= E) return;
  int dst = ei[E + e];
  atomicAdd(&cnt[dst], 1);
  atomicAdd(&easum[dst], ea[e]);
}

// thread-serial chunk of 20 + single 1024 Kogge-Stone scan
__launch_bounds__(1024)
__global__ void scan_kernel(const int* __restrict__ cnt, const float* __restrict__ easum,
                            int* __restrict__ off, float* __restrict__ loop_attr, int n){
  __shared__ int buf[1024];
  const int PER = (N_NODES + 1023)/1024;   // 20
  int t = threadIdx.x;
  int base = t*PER;
  int local[PER];
  int s = 0;
#pragma unroll
  for (int k=0;k<PER;k++){
    int i = base + k;
    int v = (i<n)? cnt[i] : 0;
    local[k] = v;
    s += v;
  }
  buf[t] = s;
  __syncthreads();
  for (int d2=1; d2<1024; d2<<=1){
    int tv = (t>=d2)? buf[t-d2] : 0;
    __syncthreads();
    buf[t] += tv;
    __syncthreads();
  }
  int run = buf[t] - s;   // exclusive prefix of this thread's chunk
#pragma unroll
  for (int k=0;k<PER;k++){
    int i = base + k;
    if (i < n){
      off[i] = run;
      int v = local[k];
      loop_attr[i] = (v>0) ? easum[i]/(float)v : 0.f;  // fill='mean'
      run += v;
    }
  }
  if (t == 1023) off[n] = buf[1023];
}

__global__ void edge_fill_kernel(const int* __restrict__ ei, const float* __restrict__ ea,
                                 const int* __restrict__ off, int* __restrict__ fill,
                                 int* __restrict__ csr_src, float* __restrict__ csr_ea, int E){
  int e = blockIdx.x*256 + threadIdx.x;
  if (e >= E) return;
  int dst = ei[E + e];
  int pos = off[dst] + atomicAdd(&fill[dst], 1);
  csr_src[pos] = ei[e];
  csr_ea[pos]  = ea[e];
}

// ---------------- conversions ----------------
// transpose: W[K,N] f32 -> Wt[N,K] f16
__global__ void wt_f16_kernel(const float* __restrict__ W, int K, int N,
                              unsigned short* __restrict__ Wt){
  __shared__ float tile[32][33];
  int k0 = blockIdx.x*32, n0 = blockIdx.y*32;
  int tx = threadIdx.x & 31, ty = threadIdx.x >> 5; // 32 x 8
  for (int r=ty; r<32; r+=8) tile[r][tx] = W[(size_t)(k0+r)*N + n0+tx];
  __syncthreads();
  for (int r=ty; r<32; r+=8){
    float w = tile[tx][r];               // = W[k0+tx][n0+r]
    Wt[(size_t)(n0+r)*K + k0+tx] = f2hu(w);
  }
}

// ---------------- cross-attention (rank-1 collapsed) ----------------
__global__ void kv_kernel(const float* __restrict__ x,
                          const float* __restrict__ kw, const float* __restrict__ kb,
                          const float* __restrict__ vw, const float* __restrict__ vb,
                          float* __restrict__ Kv, float* __restrict__ Vv){
  int j = threadIdx.x; // 256
  float ka = kb[j], va = vb[j];
  for (int k=0;k<200;k++){
    float m = x[1280+k];
    ka = fmaf(m, kw[k*256+j], ka);
    va = fmaf(m, vw[k*256+j], va);
  }
  Kv[j]=ka; Vv[j]=va;
}

__global__ void qkvo_kernel(const float* __restrict__ qw, const float* __restrict__ ow,
                            const float* __restrict__ Kv, const float* __restrict__ Vv,
                            float* __restrict__ qK, float* __restrict__ Vo){
  int idx = blockIdx.x*256 + threadIdx.x;
  if (idx < 1280){
    float a=0;
    for (int j=0;j<256;j++) a = fmaf(qw[idx*256+j], Kv[j], a);
    qK[idx]=a;
  } else if (idx < 2560){
    int j = idx-1280;
    float a=0;
    for (int i=0;i<256;i++) a = fmaf(Vv[i], ow[(size_t)i*1280+j], a);
    Vo[j]=a;
  }
}

__global__ void obw_kernel(const float* __restrict__ ob, const float* __restrict__ Vo,
                           const float* __restrict__ W, float* __restrict__ obW, float* __restrict__ VoW){
  int j = blockIdx.x*256 + threadIdx.x; // < 1024
  float a=0,b=0;
  for (int i=0;i<1280;i++){
    float w = W[(size_t)i*1024+j];
    a = fmaf(ob[i], w, a);
    b = fmaf(Vo[i], w, b);
  }
  obW[j]=a; VoW[j]=b;
}

// FUSED x f32 -> f16 conversion + scores dot (reads x once, writes Af + scores).
__launch_bounds__(256)
__global__ void xh_scores_kernel(const float* __restrict__ x, const float* __restrict__ qK,
                                 unsigned short* __restrict__ xh, float* __restrict__ scores, int n){
  __shared__ float qs[1280];
  int t = threadIdx.x;
  for (int i=t;i<1280;i+=256) qs[i]=qK[i];
  __syncthreads();
  int wid = t>>6, lane = t&63;
  int node = blockIdx.x*4 + wid;
  if (node >= n) return;
  const float* xr = x + (size_t)node*XROW;
  unsigned short* orow = xh + (size_t)node*1280;
  float acc = 0.f;
#pragma unroll
  for (int it=0; it<5; it++){
    int c4 = it*64 + lane;           // < 320
    float4 v = *(const float4*)(xr + c4*4);
    ushort4 o;
    o.x = f2hu(v.x); o.y = f2hu(v.y); o.z = f2hu(v.z); o.w = f2hu(v.w);
    *(ushort4*)(orow + c4*4) = o;
    acc = fmaf(v.x, qs[c4*4+0], acc);
    acc = fmaf(v.y, qs[c4*4+1], acc);
    acc = fmaf(v.z, qs[c4*4+2], acc);
    acc = fmaf(v.w, qs[c4*4+3], acc);
  }
  acc = wsum(acc);
  if (lane==0) scores[node] = acc;
}

__launch_bounds__(1024)
__global__ void softmax_nodes(const float* __restrict__ scores, float* __restrict__ wts, int n){
  __shared__ float red[16];
  int t = threadIdx.x, lane=t&63, wid=t>>6;
  float m = -INFINITY;
  for (int i=t;i<n;i+=1024) m = fmaxf(m, scores[i]);
  m = wmax(m);
  if (lane==0) red[wid]=m;
  __syncthreads();
  if (t==0){ float r=red[0]; for (int k=1;k<16;k++) r=fmaxf(r,red[k]); red[0]=r; }
  __syncthreads();
  float M = red[0];
  __syncthreads();
  float z=0;
  for (int i=t;i<n;i+=1024) z += __expf((scores[i]-M)*(1.f/16.f));
  z = wsum(z);
  if (lane==0) red[wid]=z;
  __syncthreads();
  if (t==0){ float r=0; for (int k=0;k<16;k++) r+=red[k]; red[0]=r; }
  __syncthreads();
  float invZ = 1.f/red[0];
  for (int i=t;i<n;i+=1024) wts[i] = __expf((scores[i]-M)*(1.f/16.f))*invZ;
}

// ============ 256x256 8-phase f16 MFMA GEMM (T2+T3+T4+T5 regime) ============
// C[M,N] = A[M,K] @ B[N,K]^T. BK=64, 512 threads = 8 waves (2M x 4N), each wave
// owns 128x64 output (8x4 16x16 frags). LDS = 2 dbuf x (A 32K | B 32K) = 128 KB.
// Per K-tile: 4 phases {ds_read subtile; stage half-tile(s); SGB; s_barrier;
// lgkmcnt(0); SGB; setprio(1); 16 MFMA; setprio(0); SGB; s_barrier; SGB}.
// Next K-tile's 4 half-tiles staged at phases 0-1 (3-4 phases of flight cover);
// ONE vmcnt(0) per K-tile at phase 3 before the trailing barrier -> loads stay
// in flight across 6 intermediate barriers (counted-wait pipeline, T4).
// XOR swizzle: 16B-chunk col ^= (row&7) -- identical family to the 128^2 kernel
// (measured SQ_LDS_BANK_CONFLICT = 0).
// N-tile(256) == one head -> epilogue writes als/ald DIRECTLY (no partials);
// block (band0,nt0) also computes we[h].
__launch_bounds__(512,2)
__global__ void gemm256_f16(const unsigned short* __restrict__ A,
                            const unsigned short* __restrict__ B,
                            unsigned short* __restrict__ C, int M, int N, int K,
                            const float* __restrict__ addCol,   // obW or null
                            const float* __restrict__ vCol,     // VoW
                            const float* __restrict__ wRow,     // wts
                            const float* __restrict__ a_src,    // [N] flat
                            const float* __restrict__ a_dst,
                            float* __restrict__ als,            // [M*H] direct
                            float* __restrict__ ald,
                            const float* __restrict__ We,       // for we fold
                            const float* __restrict__ a_edge,
                            float* __restrict__ we)
{
  __shared__ short lds[2*32768];          // 128 KB: [buf][A 16384 | B 16384] shorts

  const int ntc = N >> 8;                 // 4 (1024) ; H == ntc
  const int sh  = (ntc==4)?2:((ntc==2)?1:0);
  const int g   = blockIdx.y >> sh;
  const int nt  = blockIdx.y & (ntc - 1);
  const int band = blockIdx.x + (g << 3);
  if (band * 256 >= M) return;

  const int t = threadIdx.x;
  const int w = t>>6, l = t&63;
  const int bm = band*256, bn = nt*256;
  const int wrh = w>>2;                   // A half (0/1): rows wrh*128..+127
  const int wcl = (w&3)*64;               // col band within tile
  const int q4 = l>>4, m16 = l&15;

  f32x4v acc[8][4];
#pragma unroll
  for (int i=0;i<8;i++)
#pragma unroll
    for (int j=0;j<4;j++) acc[i][j] = (f32x4v){0.f,0.f,0.f,0.f};

  // stage pointers: chunk p = (w*2+q)*64 + l within a 16KB half-tile (128 rows x 64 k)
  const unsigned short *pA00,*pA01,*pA10,*pA11,*pB00,*pB01,*pB10,*pB11;
  int lA00,lA01,lA10,lA11,lB00,lB01,lB10,lB11;
  {
#pragma unroll
    for (int half=0; half<2; half++){
#pragma unroll
      for (int q=0; q<2; q++){
        int p  = (w*2+q)*64 + l;
        int r  = p>>3, pc = p&7;
        int kc = (pc ^ (r&7))*8;
        int rowA = bm + half*128 + r; if (rowA > M-1) rowA = M-1;
        int rowB = bn + half*128 + r;
        const unsigned short* ap = A + (size_t)rowA*K + kc;
        const unsigned short* bp = B + (size_t)rowB*K + kc;
        int la = half*8192 + (w*2+q)*512;          // shorts
        int lb = 16384 + la;
        if (half==0 && q==0){ pA00=ap; pB00=bp; lA00=la; lB00=lb; }
        if (half==0 && q==1){ pA01=ap; pB01=bp; lA01=la; lB01=lb; }
        if (half==1 && q==0){ pA10=ap; pB10=bp; lA10=la; lB10=lb; }
        if (half==1 && q==1){ pA11=ap; pB11=bp; lA11=la; lB11=lb; }
      }
    }
  }

  const int nk = K >> 6;                  // 20 / 16

  // prologue: stage K-tile 0 -> buf0
  {
    short* b0 = lds;
    async_copy16(b0 + lA00, pA00); async_copy16(b0 + lA01, pA01);
    async_copy16(b0 + lA10, pA10); async_copy16(b0 + lA11, pA11);
    async_copy16(b0 + lB00, pB00); async_copy16(b0 + lB01, pB01);
    async_copy16(b0 + lB10, pB10); async_copy16(b0 + lB11, pB11);
    asm volatile("s_waitcnt vmcnt(0)" ::: "memory");
    __builtin_amdgcn_sched_barrier(0);
    __builtin_amdgcn_s_barrier();
    __builtin_amdgcn_sched_barrier(0);
  }

  for (int kt = 0; kt < nk; ++kt){
    short* cur = lds + (kt&1)*32768;
    short* nxt = lds + ((kt+1)&1)*32768;
    const bool pre = (kt+1 < nk);
    const size_t kofs = (size_t)(kt+1)*64;

    f16x8 bf[4];
#pragma unroll
    for (int ph = 0; ph < 4; ++ph){
      const int ks = ph >> 1, ih = ph & 1;
      const int c  = ks*4 + q4;
      // ---- ds_read this phase's fragments ----
      f16x8 af[4];
#pragma unroll
      for (int ii=0; ii<4; ii++){
        int rl = (ih*4+ii)*16 + m16;                 // 0..127 within wave's A half
        af[ii] = *(const f16x8*)&cur[ wrh*8192 + rl*64 + ((c ^ (rl&7))*8) ];
      }
      if (ih == 0){
#pragma unroll
        for (int j=0;j<4;j++){
          int rb = wcl + j*16 + m16;                 // 0..255 within B region
          bf[j] = *(const f16x8*)&cur[ 16384 + rb*64 + ((c ^ (rb&7))*8) ];
        }
      }
      // ---- stage next K-tile (phases 0-1: 3-4 phases of latency cover) ----
      if (pre){
        if (ph == 0){
          async_copy16(nxt + lA00, pA00 + kofs); async_copy16(nxt + lA01, pA01 + kofs);
          async_copy16(nxt + lA10, pA10 + kofs); async_copy16(nxt + lA11, pA11 + kofs);
        } else if (ph == 1){
          async_copy16(nxt + lB00, pB00 + kofs); async_copy16(nxt + lB01, pB01 + kofs);
          async_copy16(nxt + lB10, pB10 + kofs); async_copy16(nxt + lB11, pB11 + kofs);
        }
      }
      __builtin_amdgcn_sched_barrier(0);
      __builtin_amdgcn_s_barrier();
      asm volatile("s_waitcnt lgkmcnt(0)" ::: "memory");
      __builtin_amdgcn_sched_barrier(0);

      __builtin_amdgcn_s_setprio(1);
#pragma unroll
      for (int ii=0; ii<4; ii++)
#pragma unroll
        for (int j=0; j<4; j++)
          acc[ih*4+ii][j] = __builtin_amdgcn_mfma_f32_16x16x32_f16(af[ii], bf[j], acc[ih*4+ii][j], 0,0,0);
      __builtin_amdgcn_s_setprio(0);
      __builtin_amdgcn_sched_barrier(0);
      if (ph == 3){
        // all waves drain their stage-loads before anyone reads the next buffer
        asm volatile("s_waitcnt vmcnt(0)" ::: "memory");
        __builtin_amdgcn_sched_barrier(0);
      }
      __builtin_amdgcn_s_barrier();
      __builtin_amdgcn_sched_barrier(0);
    }
  }

  // ---- epilogue: C store (+L0 fusion) + direct als/ald + we fold ----
  __syncthreads();
  float* sred = (float*)lds;              // [4 bands][256 rows]
  float* dred = sred + 1024;
  const int bandc = w & 3;

  float asv[4], adv[4];
#pragma unroll
  for (int j=0;j<4;j++){
    int n = bn + wcl + j*16 + m16;
    asv[j] = a_src[n];
    adv[j] = a_dst[n];
  }
#pragma unroll
  for (int i=0;i<8;i++){
#pragma unroll
    for (int r=0;r<4;r++){
      int rloc = wrh*128 + i*16 + q4*4 + r;
      int m = bm + rloc;
      float wrow = addCol ? wRow[m < M ? m : M-1] : 0.f;
      float vj[4];
#pragma unroll
      for (int j=0;j<4;j++){
        int n = bn + wcl + j*16 + m16;
        float v = acc[i][j][r];
        if (addCol) v += addCol[n] + wrow*vCol[n];
        vj[j] = v;
      }
      if (m < M){
        unsigned short* crow = C + (size_t)m*N;
#pragma unroll
        for (int j=0;j<4;j++) crow[bn + wcl + j*16 + m16] = f2hu(vj[j]);
      }
      float s = vj[0]*asv[0] + vj[1]*asv[1] + vj[2]*asv[2] + vj[3]*asv[3];
      float d = vj[0]*adv[0] + vj[1]*adv[1] + vj[2]*adv[2] + vj[3]*adv[3];
#pragma unroll
      for (int o=1;o<16;o<<=1){ s += __shfl_xor(s,o); d += __shfl_xor(d,o); }
      if (m16 == 0){
        sred[bandc*256 + rloc] = s;
        dred[bandc*256 + rloc] = d;
      }
    }
  }
  __syncthreads();
  if (t < 256){
    int m = bm + t;
    if (m < M){
      float s = sred[t] + sred[256+t] + sred[512+t] + sred[768+t];
      float d = dred[t] + dred[256+t] + dred[512+t] + dred[768+t];
      als[(size_t)m*ntc + nt] = s;
      ald[(size_t)m*ntc + nt] = d;
    }
  }
  // we fold (once per launch)
  if (band == 0 && nt == 0 && w < ntc){
    float4 a = ((const float4*)(We + w*256))[l];
    float4 b = ((const float4*)(a_edge + w*256))[l];
    float v = a.x*b.x + a.y*b.y + a.z*b.z + a.w*b.w;
    v = wsum(v);
    if (l==0) we[w]=v;
  }
}

// ---------------- 128x128 2-phase GEMM (kept for layer 2: N=256) ----------------
__launch_bounds__(256)
__global__ void gemm_f16(const unsigned short* __restrict__ A,
                         const unsigned short* __restrict__ B,
                         unsigned short* __restrict__ C, int M, int N, int K,
                         const float* __restrict__ addCol,   // obW or null
                         const float* __restrict__ vCol,     // VoW
                         const float* __restrict__ wRow,     // wts
                         const float* __restrict__ a_src,    // [N] flat
                         const float* __restrict__ a_dst,
                         float* __restrict__ alsp,           // [ntc][M] partials
                         float* __restrict__ aldp)
{
  __shared__ short lds[2*2*128*64];

  const int ntc = N >> 7;                 // N-tiles (pow2)
  const int sh  = __popc(ntc - 1);
  const int g   = blockIdx.y >> sh;
  const int nt  = blockIdx.y & (ntc - 1);
  const int band = blockIdx.x + (g << 3);
  if (band * 128 >= M) return;

  const int t = threadIdx.x;
  const int w = t>>6, l = t&63;
  const int bm = band*128, bn = nt*128;
  const int wr = (w>>1)*64, wc = (w&1)*64;
  const int half = w & 1;

  f32x4v acc[4][4];
#pragma unroll
  for (int i=0;i<4;i++)
#pragma unroll
    for (int j=0;j<4;j++) acc[i][j] = (f32x4v){0.f,0.f,0.f,0.f};

  const unsigned short* Ap[4]; const unsigned short* Bp[4];
  int ldsOff[4];
#pragma unroll
  for (int q=0;q<4;q++){
    int p  = (w*4+q)*64 + l;
    int r  = p>>3, pc = p&7;
    int kc = (pc ^ (r&7))*8;
    int rowA = bm + r; if (rowA > M-1) rowA = M-1;
    Ap[q] = A + (size_t)rowA*K + kc;
    Bp[q] = B + (size_t)(bn+r)*K + kc;
    ldsOff[q] = (w*4+q)*64*8;
  }

  const int nsteps = K >> 6;

#pragma unroll
  for (int q=0;q<4;q++) async_copy16(lds + ldsOff[q],        Ap[q]);
#pragma unroll
  for (int q=0;q<4;q++) async_copy16(lds + 8192 + ldsOff[q], Bp[q]);

  const int q4 = l>>4, m16 = l&15;

  for (int ks0=0; ks0<nsteps; ++ks0){
    short* curb = lds + (ks0&1)*16384;

    if (ks0+1 < nsteps){
      short* nxt = lds + ((ks0+1)&1)*16384;
      const int k0n = (ks0+1)*64;
#pragma unroll
      for (int q=0;q<4;q++) async_copy16(nxt + ldsOff[q],        Ap[q] + k0n);
#pragma unroll
      for (int q=0;q<4;q++) async_copy16(nxt + 8192 + ldsOff[q], Bp[q] + k0n);
      asm volatile("s_waitcnt vmcnt(8)" ::: "memory");
    } else {
      asm volatile("s_waitcnt vmcnt(0)" ::: "memory");
    }
    __builtin_amdgcn_sched_barrier(0);
    __builtin_amdgcn_s_barrier();
    __builtin_amdgcn_sched_barrier(0);

    __builtin_amdgcn_s_setprio(1);
#pragma unroll
    for (int ks=0; ks<2; ks++){
      f16x8 af[4], bf[4];
      const int c = ks*4 + q4;
#pragma unroll
      for (int i=0;i<4;i++){
        int ra = wr + i*16 + m16;
        af[i] = *(const f16x8*)&curb[ra*64 + ((c ^ (ra&7))*8)];
        int rb = wc + i*16 + m16;
        bf[i] = *(const f16x8*)&curb[8192 + rb*64 + ((c ^ (rb&7))*8)];
      }
#pragma unroll
      for (int i=0;i<4;i++)
#pragma unroll
        for (int j=0;j<4;j++)
          acc[i][j] = __builtin_amdgcn_mfma_f32_16x16x32_f16(af[i], bf[j], acc[i][j], 0,0,0);
    }
    __builtin_amdgcn_s_setprio(0);
    __builtin_amdgcn_sched_barrier(0);
    __builtin_amdgcn_s_barrier();
    __builtin_amdgcn_sched_barrier(0);
  }

  float* sred = (float*)lds;          // [2][128]
  float* dred = sred + 256;
  float asv[4], adv[4];
#pragma unroll
  for (int j=0;j<4;j++){
    int n = bn + wc + j*16 + m16;
    asv[j] = a_src[n];
    adv[j] = a_dst[n];
  }
#pragma unroll
  for (int i=0;i<4;i++){
#pragma unroll
    for (int r=0;r<4;r++){
      int rloc = wr + i*16 + q4*4 + r;
      int m = bm + rloc;
      float wrow = addCol ? wRow[m < M ? m : M-1] : 0.f;
      float vj[4];
#pragma unroll
      for (int j=0;j<4;j++){
        int n = bn + wc + j*16 + m16;
        float v = acc[i][j][r];
        if (addCol) v += addCol[n] + wrow*vCol[n];
        vj[j] = v;
      }
      if (m < M){
        unsigned short* crow = C + (size_t)m*N;
#pragma unroll
        for (int j=0;j<4;j++) crow[bn + wc + j*16 + m16] = f2hu(vj[j]);
      }
      float s = vj[0]*asv[0] + vj[1]*asv[1] + vj[2]*asv[2] + vj[3]*asv[3];
      float d = vj[0]*adv[0] + vj[1]*adv[1] + vj[2]*adv[2] + vj[3]*adv[3];
#pragma unroll
      for (int o=1;o<16;o<<=1){ s += __shfl_xor(s,o); d += __shfl_xor(d,o); }
      if (m16 == 0){
        sred[half*128 + rloc] = s;
        dred[half*128 + rloc] = d;
      }
    }
  }
  __syncthreads();
  if (t < 128){
    int m = bm + t;
    if (m < M){
      alsp[(size_t)nt*M + m] = sred[t] + sred[128+t];
      aldp[(size_t)nt*M + m] = dred[t] + dred[128+t];
    }
  }
}

// combine per-tile partials -> als/ald (layer 2 only); block 0 computes we[h].
__global__ void als_combine(const float* __restrict__ alsp, const float* __restrict__ aldp,
                            float* __restrict__ als, float* __restrict__ ald, int M, int H,
                            const float* __restrict__ We, const float* __restrict__ a_edge,
                            float* __restrict__ we){
  if (blockIdx.x == 0){
    int wid = threadIdx.x>>6, lane = threadIdx.x&63;
    if (wid < H){
      const float4* w4 = (const float4*)(We + wid*256);
      const float4* a4 = (const float4*)(a_edge + wid*256);
      float4 a = w4[lane], b = a4[lane];
      float v = a.x*b.x + a.y*b.y + a.z*b.z + a.w*b.w;
      v = wsum(v);
      if (lane==0) we[wid]=v;
    }
  }
  int idx = blockIdx.x*256 + threadIdx.x;
  if (idx >= M*H) return;
  int m = idx / H, hh = idx - m*H;
  als[idx] = alsp[(size_t)(2*hh)*M + m] + alsp[(size_t)(2*hh+1)*M + m];
  ald[idx] = aldp[(size_t)(2*hh)*M + m] + aldp[(size_t)(2*hh+1)*M + m];
}

// ---------------- fused alpha-softmax + aggregate + bias + LN + ReLU ----------------
template<int H>
__launch_bounds__(256)
__global__ void gat_agg_ln_wave(const unsigned short* __restrict__ hmat,
                           const float* __restrict__ als, const float* __restrict__ ald,
                           const int* __restrict__ off, const int* __restrict__ csr_src,
                           const float* __restrict__ csr_ea, const float* __restrict__ loop_attr,
                           const float* __restrict__ we,
                           const float* __restrict__ bias,
                           const float* __restrict__ ln_g, const float* __restrict__ ln_b,
                           float* __restrict__ outf, unsigned short* __restrict__ outb, int n)
{
  constexpr int OUT = 256*H;      // 1024 or 256
  constexpr int CPL = OUT/64;     // channels per lane: 16 or 4
  const int wv = threadIdx.x>>6, lane = threadIdx.x&63;
  const int i = blockIdx.x*4 + wv;
  __shared__ float wbuf_s[4][64*H];
  __shared__ int   sbuf_s[4][64];
  if (i >= n) return;
  float* wbuf = wbuf_s[wv];
  int*   sbuf = sbuf_s[wv];

  const int begin = off[i];
  const int deg   = off[i+1]-begin;
  const int S     = deg + 1;           // + self-loop

  float aldi[H], wei[H];
#pragma unroll
  for (int hh=0;hh<H;hh++){ aldi[hh]=ald[(size_t)i*H+hh]; wei[hh]=we[hh]; }
  const float lea = loop_attr[i];

  const int head = (lane*CPL) >> 8;
  const int c0   = lane*CPL;
  float acc[CPL];
#pragma unroll
  for (int c=0;c<CPL;c++) acc[c]=0.f;

  if (S <= 64){
    int src = i; float ev = lea;
    if (lane < deg){ src = csr_src[begin+lane]; ev = csr_ea[begin+lane]; }
    const bool act = lane < S;
    sbuf[lane] = src;

    if constexpr (CPL==16){
      u16x8 a0r0,a0r1,a1r0,a1r1;
      {
        const unsigned short* r0p = hmat + (size_t)sbuf[0]*OUT + c0;
        a0r0 = *(const u16x8*)r0p; a0r1 = *(const u16x8*)(r0p+8);
        a1r0 = a0r0; a1r1 = a0r1;
        if (S > 1){
          const unsigned short* r1p = hmat + (size_t)sbuf[1]*OUT + c0;
          a1r0 = *(const u16x8*)r1p; a1r1 = *(const u16x8*)(r1p+8);
        }
      }
      float a[H];
#pragma unroll
      for (int hh=0;hh<H;hh++){
        float v = als[(size_t)src*H+hh] + aldi[hh] + ev*wei[hh];
        a[hh] = v>0.f ? v : 0.2f*v;
      }
#pragma unroll
      for (int hh=0;hh<H;hh++){
        float M = wmax_all(act ? a[hh] : -INFINITY);
        float e = act ? __expf(a[hh]-M) : 0.f;
        float Z = wsum_all(e);
        wbuf[lane*H+hh] = e / (Z + 1e-16f);
      }
      int j = 0;
      for (; j+2<S; j+=2){
        u16x8 n0r0,n0r1,n1r0,n1r1;
        {
          const unsigned short* rp = hmat + (size_t)sbuf[j+2]*OUT + c0;
          n0r0 = *(const u16x8*)rp; n0r1 = *(const u16x8*)(rp+8);
          n1r0 = n0r0; n1r1 = n0r1;
          if (j+3 < S){
            const unsigned short* rq = hmat + (size_t)sbuf[j+3]*OUT + c0;
            n1r0 = *(const u16x8*)rq; n1r1 = *(const u16x8*)(rq+8);
          }
        }
        float w0 = wbuf[j*H+head], w1 = wbuf[(j+1)*H+head];
#pragma unroll
        for (int c=0;c<8;c++){
          acc[c]   = fmaf(w0, hu2f(a0r0[c]), acc[c]);
          acc[8+c] = fmaf(w0, hu2f(a0r1[c]), acc[8+c]);
        }
#pragma unroll
        for (int c=0;c<8;c++){
          acc[c]   = fmaf(w1, hu2f(a1r0[c]), acc[c]);
          acc[8+c] = fmaf(w1, hu2f(a1r1[c]), acc[8+c]);
        }
        a0r0=n0r0; a0r1=n0r1; a1r0=n1r0; a1r1=n1r1;
      }
      {
        float w0 = wbuf[j*H+head];
#pragma unroll
        for (int c=0;c<8;c++){
          acc[c]   = fmaf(w0, hu2f(a0r0[c]), acc[c]);
          acc[8+c] = fmaf(w0, hu2f(a0r1[c]), acc[8+c]);
        }
        if (j+1 < S){
          float w1 = wbuf[(j+1)*H+head];
#pragma unroll
          for (int c=0;c<8;c++){
            acc[c]   = fmaf(w1, hu2f(a1r0[c]), acc[c]);
            acc[8+c] = fmaf(w1, hu2f(a1r1[c]), acc[8+c]);
          }
        }
      }
    } else {
      ushort4 a0, a1;
      {
        a0 = *(const ushort4*)(hmat + (size_t)sbuf[0]*OUT + c0);
        a1 = a0;
        if (S > 1) a1 = *(const ushort4*)(hmat + (size_t)sbuf[1]*OUT + c0);
      }
      float a[H];
#pragma unroll
      for (int hh=0;hh<H;hh++){
        float v = als[(size_t)src*H+hh] + aldi[hh] + ev*wei[hh];
        a[hh] = v>0.f ? v : 0.2f*v;
      }
#pragma unroll
      for (int hh=0;hh<H;hh++){
        float M = wmax_all(act ? a[hh] : -INFINITY);
        float e = act ? __expf(a[hh]-M) : 0.f;
        float Z = wsum_all(e);
        wbuf[lane*H+hh] = e / (Z + 1e-16f);
      }
      int j = 0;
      for (; j+2<S; j+=2){
        ushort4 n0, n1;
        n0 = *(const ushort4*)(hmat + (size_t)sbuf[j+2]*OUT + c0);
        n1 = n0;
        if (j+3 < S) n1 = *(const ushort4*)(hmat + (size_t)sbuf[j+3]*OUT + c0);
        float w0 = wbuf[j*H+head], w1 = wbuf[(j+1)*H+head];
        acc[0]=fmaf(w0,hu2f(a0.x),acc[0]); acc[1]=fmaf(w0,hu2f(a0.y),acc[1]);
        acc[2]=fmaf(w0,hu2f(a0.z),acc[2]); acc[3]=fmaf(w0,hu2f(a0.w),acc[3]);
        acc[0]=fmaf(w1,hu2f(a1.x),acc[0]); acc[1]=fmaf(w1,hu2f(a1.y),acc[1]);
        acc[2]=fmaf(w1,hu2f(a1.z),acc[2]); acc[3]=fmaf(w1,hu2f(a1.w),acc[3]);
        a0=n0; a1=n1;
      }
      {
        float w0 = wbuf[j*H+head];
        acc[0]=fmaf(w0,hu2f(a0.x),acc[0]); acc[1]=fmaf(w0,hu2f(a0.y),acc[1]);
        acc[2]=fmaf(w0,hu2f(a0.z),acc[2]); acc[3]=fmaf(w0,hu2f(a0.w),acc[3]);
        if (j+1 < S){
          float w1 = wbuf[(j+1)*H+head];
          acc[0]=fmaf(w1,hu2f(a1.x),acc[0]); acc[1]=fmaf(w1,hu2f(a1.y),acc[1]);
          acc[2]=fmaf(w1,hu2f(a1.z),acc[2]); acc[3]=fmaf(w1,hu2f(a1.w),acc[3]);
        }
      }
    }
  } else {
    float rm[H];
#pragma unroll
    for (int hh=0;hh<H;hh++) rm[hh] = -INFINITY;
    for (int s=lane; s<S; s+=64){
      int src = (s<deg)? csr_src[begin+s] : i;
      float ev = (s<deg)? csr_ea[begin+s] : lea;
#pragma unroll
      for (int hh=0;hh<H;hh++){
        float v = als[(size_t)src*H+hh] + aldi[hh] + ev*wei[hh];
        v = v>0.f? v : 0.2f*v;
        rm[hh] = fmaxf(rm[hh], v);
      }
    }
    float M[H], es[H];
#pragma unroll
    for (int hh=0;hh<H;hh++){ M[hh]=wmax_all(rm[hh]); es[hh]=0.f; }
    for (int s=lane; s<S; s+=64){
      int src = (s<deg)? csr_src[begin+s] : i;
      float ev = (s<deg)? csr_ea[begin+s] : lea;
#pragma unroll
      for (int hh=0;hh<H;hh++){
        float v = als[(size_t)src*H+hh] + aldi[hh] + ev*wei[hh];
        v = v>0.f? v : 0.2f*v;
        es[hh] += __expf(v - M[hh]);
      }
    }
    float invZ[H];
#pragma unroll
    for (int hh=0;hh<H;hh++) invZ[hh] = 1.f/(wsum_all(es[hh]) + 1e-16f);
    for (int cb=0; cb<S; cb+=64){
      int m = min(64, S-cb);
      int s = cb + lane;
      if (s < S){
        int src = (s<deg)? csr_src[begin+s] : i;
        float ev = (s<deg)? csr_ea[begin+s] : lea;
        sbuf[lane] = src;
#pragma unroll
        for (int hh=0;hh<H;hh++){
          float v = als[(size_t)src*H+hh] + aldi[hh] + ev*wei[hh];
          v = v>0.f? v : 0.2f*v;
          wbuf[lane*H+hh] = __expf(v - M[hh]) * invZ[hh];
        }
      }
      for (int j=0;j<m;j++){
        int sj = sbuf[j];
        float wj = wbuf[j*H+head];
        const unsigned short* row = hmat + (size_t)sj*OUT + c0;
        if constexpr (CPL==16){
          u16x8 r0 = *(const u16x8*)(row);
          u16x8 r1 = *(const u16x8*)(row+8);
#pragma unroll
          for (int c=0;c<8;c++){
            acc[c]   = fmaf(wj, hu2f(r0[c]), acc[c]);
            acc[8+c] = fmaf(wj, hu2f(r1[c]), acc[8+c]);
          }
        } else {
          ushort4 r = *(const ushort4*)(row);
          acc[0]=fmaf(wj,hu2f(r.x),acc[0]); acc[1]=fmaf(wj,hu2f(r.y),acc[1]);
          acc[2]=fmaf(wj,hu2f(r.z),acc[2]); acc[3]=fmaf(wj,hu2f(r.w),acc[3]);
        }
      }
    }
  }

  // ---- bias + LayerNorm + ReLU (wave-level) ----
  float vals[CPL];
  float ls=0.f;
#pragma unroll
  for (int c=0;c<CPL;c+=4){
    float4 b4 = *(const float4*)(bias + c0 + c);
    vals[c]=acc[c]+b4.x; vals[c+1]=acc[c+1]+b4.y; vals[c+2]=acc[c+2]+b4.z; vals[c+3]=acc[c+3]+b4.w;
    ls += vals[c]+vals[c+1]+vals[c+2]+vals[c+3];
  }
  float mu = wsum_all(ls) * (1.f/OUT);
  float lv=0.f;
#pragma unroll
  for (int c=0;c<CPL;c++){ float d=vals[c]-mu; lv += d*d; }
  float inv = rsqrtf(wsum_all(lv)*(1.f/OUT) + 1e-5f);

  if (outb){
    if constexpr (CPL==16){
#pragma unroll
      for (int c=0;c<CPL;c+=8){
        u16x8 o;
#pragma unroll
        for (int k=0;k<8;k++){
          float g = ln_g[c0+c+k], b = ln_b[c0+c+k];
          o[k] = f2hu(fmaxf((vals[c+k]-mu)*inv*g + b, 0.f));
        }
        *(u16x8*)(outb + (size_t)i*OUT + c0 + c) = o;
      }
    } else {
      ushort4 o;
      o.x = f2hu(fmaxf((vals[0]-mu)*inv*ln_g[c0+0] + ln_b[c0+0], 0.f));
      o.y = f2hu(fmaxf((vals[1]-mu)*inv*ln_g[c0+1] + ln_b[c0+1], 0.f));
      o.z = f2hu(fmaxf((vals[2]-mu)*inv*ln_g[c0+2] + ln_b[c0+2], 0.f));
      o.w = f2hu(fmaxf((vals[3]-mu)*inv*ln_g[c0+3] + ln_b[c0+3], 0.f));
      *(ushort4*)(outb + (size_t)i*OUT + c0) = o;
    }
  } else {
#pragma unroll
    for (int c=0;c<CPL;c+=4){
      float4 g4 = *(const float4*)(ln_g + c0 + c);
      float4 b4 = *(const float4*)(ln_b + c0 + c);
      float4 o;
      o.x = fmaxf((vals[c+0]-mu)*inv*g4.x + b4.x, 0.f);
      o.y = fmaxf((vals[c+1]-mu)*inv*g4.y + b4.y, 0.f);
      o.z = fmaxf((vals[c+2]-mu)*inv*g4.z + b4.z, 0.f);
      o.w = fmaxf((vals[c+3]-mu)*inv*g4.w + b4.w, 0.f);
      *(float4*)(outf + (size_t)i*OUT + c0 + c) = o;
    }
  }
}

// ---------------- mean pool + classifier ----------------
__global__ void colsum_kernel(const float* __restrict__ h2, float* __restrict__ gsum, int n){
  int c = threadIdx.x; // 256
  float acc=0;
  for (int i=blockIdx.x;i<n;i+=gridDim.x) acc += h2[(size_t)i*256 + c];
  atomicAdd(&gsum[c], acc);
}

__launch_bounds__(128)
__global__ void cls_kernel(const float* __restrict__ gsum,
                           const float* __restrict__ w1, const float* __restrict__ b1,
                           const float* __restrict__ w2, const float* __restrict__ b2,
                           float* __restrict__ outp){
  __shared__ float g[256];
  __shared__ float hid[128];
  int t = threadIdx.x;
  g[t]     = gsum[t]    *(1.f/N_NODES);
  g[t+128] = gsum[t+128]*(1.f/N_NODES);
  __syncthreads();
  float a = b1[t];
  for (int c=0;c<256;c++) a = fmaf(g[c], w1[c*128+t], a);
  hid[t] = fmaxf(a, 0.f);
  __syncthreads();
  if (t<2){
    float o = b2[t];
    for (int j=0;j<128;j++) o = fmaf(hid[j], w2[j*2+t], o);
    outp[t] = o;
  }
}

// ---------------- launch ----------------
extern "C" void kernel_launch(void* const* d_in, const int* in_sizes, int n_in,
                              void* d_out, int out_size, void* d_ws, size_t ws_size,
                              hipStream_t stream)
{
  const float* x      = (const float*)d_in[0];
  const int*   ei     = (const int*)  d_in[1];
  const float* ea     = (const float*)d_in[2];
  const float* ca_qw  = (const float*)d_in[3];
  const float* ca_kw  = (const float*)d_in[5];
  const float* ca_kb  = (const float*)d_in[6];
  const float* ca_vw  = (const float*)d_in[7];
  const float* ca_vb  = (const float*)d_in[8];
  const float* ca_ow  = (const float*)d_in[9];
  const float* ca_ob  = (const float*)d_in[10];
  const float* g0_w   = (const float*)d_in[11];
  const float* g0_ew  = (const float*)d_in[12];
  const float* g0_as  = (const float*)d_in[13];
  const float* g0_ad  = (const float*)d_in[14];
  const float* g0_ae  = (const float*)d_in[15];
  const float* g0_b   = (const float*)d_in[16];
  const float* ln0_g  = (const float*)d_in[17];
  const float* ln0_b  = (const float*)d_in[18];
  const float* g1_w   = (const float*)d_in[19];
  const float* g1_ew  = (const float*)d_in[20];
  const float* g1_as  = (const float*)d_in[21];
  const float* g1_ad  = (const float*)d_in[22];
  const float* g1_ae  = (const float*)d_in[23];
  const float* g1_b   = (const float*)d_in[24];
  const float* ln1_g  = (const float*)d_in[25];
  const float* ln1_b  = (const float*)d_in[26];
  const float* g2_w   = (const float*)d_in[27];
  const float* g2_ew  = (const float*)d_in[28];
  const float* g2_as  = (const float*)d_in[29];
  const float* g2_ad  = (const float*)d_in[30];
  const float* g2_ae  = (const float*)d_in[31];
  const float* g2_b   = (const float*)d_in[32];
  const float* ln2_g  = (const float*)d_in[33];
  const float* ln2_b  = (const float*)d_in[34];
  const float* cls_w1 = (const float*)d_in[35];
  const float* cls_b1 = (const float*)d_in[36];
  const float* cls_w2 = (const float*)d_in[37];
  const float* cls_b2 = (const float*)d_in[38];
  float* outp = (float*)d_out;

  const int N = N_NODES, E = N_EDGES;

  char* base = (char*)d_ws;
  size_t o = 0;
  auto alloc = [&](size_t bytes)->void*{
    void* p = base + o;
    o += (bytes + 255) & ~(size_t)255;
    return p;
  };
  unsigned short* hF   = (unsigned short*)alloc((size_t)N*1024*2); // GEMM output h (f16)
  unsigned short* Af   = (unsigned short*)alloc((size_t)N*1280*2); // f16 activations (x, then agg out)
  float*          h2   = (float*)         alloc((size_t)N*256*4);  // layer-2 agg out (f32)
  unsigned short* Wt   = (unsigned short*)alloc((size_t)1280*1024*2);
  float* alsp      = (float*)alloc((size_t)8*N*4);    // per-tile partials (layer 2)
  float* aldp      = (float*)alloc((size_t)8*N*4);
  float* als       = (float*)alloc((size_t)2*N*4*4);  // als | ald contiguous
  float* ald       = als + (size_t)N*4;
  float* scores    = (float*)alloc((size_t)N*4);
  float* wts       = (float*)alloc((size_t)N*4);
  int*   cnt       = (int*)  alloc((size_t)N*4);
  float* easum     = (float*)alloc((size_t)N*4);
  int*   off       = (int*)  alloc((size_t)(N+1)*4);
  int*   fill      = (int*)  alloc((size_t)N*4);
  int*   csr_src   = (int*)  alloc((size_t)E*4);
  float* csr_ea    = (float*)alloc((size_t)E*4);
  float* loop_attr = (float*)alloc((size_t)N*4);
  float* Kv        = (float*)alloc(256*4);
  float* Vv        = (float*)alloc(256*4);
  float* qK        = (float*)alloc(1280*4);
  float* Vo        = (float*)alloc(1280*4);
  float* obW       = (float*)alloc(1024*4);
  float* VoW       = (float*)alloc(1024*4);
  float* web       = (float*)alloc(16*4);
  float* gsum      = (float*)alloc(256*4);

  hipMemsetAsync(cnt,   0, (size_t)N*4, stream);
  hipMemsetAsync(easum, 0, (size_t)N*4, stream);
  hipMemsetAsync(fill,  0, (size_t)N*4, stream);
  hipMemsetAsync(gsum,  0, 256*4,       stream);

  // ---- edge preprocessing (CSR by dst) ----
  int eblocks = (E + 255)/256;
  edge_count_kernel<<<eblocks,256,0,stream>>>(ei, ea, cnt, easum, E);
  scan_kernel<<<1,1024,0,stream>>>(cnt, easum, off, loop_attr, N);
  edge_fill_kernel<<<eblocks,256,0,stream>>>(ei, ea, off, fill, csr_src, csr_ea, E);

  // ---- cross-attention, rank-1 collapsed ----
  kv_kernel<<<1,256,0,stream>>>(x, ca_kw, ca_kb, ca_vw, ca_vb, Kv, Vv);
  qkvo_kernel<<<10,256,0,stream>>>(ca_qw, ca_ow, Kv, Vv, qK, Vo);
  xh_scores_kernel<<<(N+3)/4,256,0,stream>>>(x, qK, Af, scores, N);
  obw_kernel<<<4,256,0,stream>>>(ca_ob, Vo, g0_w, obW, VoW);
  softmax_nodes<<<1,1024,0,stream>>>(scores, wts, N);

  const int mTiles  = (N + 127)/128;        // 157 (layer-2 gemm)
  const int mGroups = (mTiles + 7)/8;       // 20
  const int mT256   = (N + 255)/256;        // 79
  const int mG256   = (mT256 + 7)/8;        // 10
  const int NB4 = (N + 3)/4;                // wave-per-node blocks

  // ---- layer 0 (256^2 8-phase GEMM, direct als + we fold) ----
  wt_f16_kernel<<<dim3(1280/32, 1024/32),256,0,stream>>>(g0_w, 1280, 1024, Wt);
  gemm256_f16<<<dim3(8, mG256*4),512,0,stream>>>(Af, Wt, hF, N, 1024, 1280, obW, VoW, wts,
                                                 g0_as, g0_ad, als, ald, g0_ew, g0_ae, web);
  gat_agg_ln_wave<4><<<NB4,256,0,stream>>>(hF, als, ald, off, csr_src, csr_ea, loop_attr,
                                           web, g0_b, ln0_g, ln0_b, nullptr, Af, N);

  // ---- layer 1 ----
  wt_f16_kernel<<<dim3(1024/32, 1024/32),256,0,stream>>>(g1_w, 1024, 1024, Wt);
  gemm256_f16<<<dim3(8, mG256*4),512,0,stream>>>(Af, Wt, hF, N, 1024, 1024, nullptr, nullptr, nullptr,
                                                 g1_as, g1_ad, als, ald, g1_ew, g1_ae, web);
  gat_agg_ln_wave<4><<<NB4,256,0,stream>>>(hF, als, ald, off, csr_src, csr_ea, loop_attr,
                                           web, g1_b, ln1_g, ln1_b, nullptr, Af, N);

  // ---- layer 2 (1 head, 256 out; 128^2 GEMM, better balance at N=256) ----
  wt_f16_kernel<<<dim3(1024/32, 256/32),256,0,stream>>>(g2_w, 1024, 256, Wt);
  gemm_f16<<<dim3(8, mGroups*2),256,0,stream>>>(Af, Wt, hF, N, 256, 1024, nullptr, nullptr, nullptr,
                                                g2_as, g2_ad, alsp, aldp);
  als_combine<<<(N+255)/256,256,0,stream>>>(alsp, aldp, als, ald, N, 1, g2_ew, g2_ae, web);
  gat_agg_ln_wave<1><<<NB4,256,0,stream>>>(hF, als, ald, off, csr_src, csr_ea, loop_attr,
                                           web, g2_b, ln2_g, ln2_b, h2, nullptr, N);

  // ---- mean pool + classifier ----
  colsum_kernel<<<256,256,0,stream>>>(h2, gsum, N);
  cls_kernel<<<1,128,0,stream>>>(gsum, cls_w1, cls_b1, cls_w2, cls_b2, outp);

  (void)in_sizes; (void)n_in; (void)out_size; (void)ws_size;
}

// Round 4
// 858.729 us; speedup vs baseline: 1.0495x; 1.0495x over previous
//
#include <hip/hip_runtime.h>
#include <hip/hip_bf16.h>
#include <math.h>

#define N_NODES 20000
#define N_EDGES 200000
#define XROW    1480   // EMB + MD

typedef __attribute__((ext_vector_type(8))) _Float16 f16x8;
typedef __attribute__((ext_vector_type(8))) unsigned short u16x8;
typedef __attribute__((ext_vector_type(4))) float f32x4v;

// ---------------- reduction helpers ----------------
__device__ __forceinline__ float wsum(float v){
#pragma unroll
  for (int o=32;o>0;o>>=1) v += __shfl_down(v,o);
  return v;
}
__device__ __forceinline__ float wmax(float v){
#pragma unroll
  for (int o=32;o>0;o>>=1) v = fmaxf(v,__shfl_down(v,o));
  return v;
}
// butterfly: result in ALL lanes
__device__ __forceinline__ float wsum_all(float v){
#pragma unroll
  for (int o=32;o>0;o>>=1) v += __shfl_xor(v,o);
  return v;
}
__device__ __forceinline__ float wmax_all(float v){
#pragma unroll
  for (int o=32;o>0;o>>=1) v = fmaxf(v,__shfl_xor(v,o));
  return v;
}

__device__ __forceinline__ unsigned short f2hu(float f){
  _Float16 h = (_Float16)f;
  return __builtin_bit_cast(unsigned short, h);
}
__device__ __forceinline__ float hu2f(unsigned short u){
  return (float)__builtin_bit_cast(_Float16, u);
}

__device__ __forceinline__ void async_copy16(void* lds, const void* g){
  __builtin_amdgcn_global_load_lds((const __attribute__((address_space(1))) void*)g,
                                   (__attribute__((address_space(3))) void*)lds, 16, 0, 0);
}

// ---------------- edge preprocessing (once, reused 3 layers) ----------------
__global__ void edge_count_kernel(const int* __restrict__ ei, const float* __restrict__ ea,
                                  int* __restrict__ cnt, float* __restrict__ easum, int E){
  int e = blockIdx.x*256 + threadIdx.x;
  if (e >= E) return;
  int dst = ei[E + e];
  atomicAdd(&cnt[dst], 1);
  atomicAdd(&easum[dst], ea[e]);
}

// thread-serial chunk of 20 + single 1024 Kogge-Stone scan
__launch_bounds__(1024)
__global__ void scan_kernel(const int* __restrict__ cnt, const float* __restrict__ easum,
                            int* __restrict__ off, float* __restrict__ loop_attr, int n){
  __shared__ int buf[1024];
  const int PER = (N_NODES + 1023)/1024;   // 20
  int t = threadIdx.x;
  int base = t*PER;
  int local[PER];
  int s = 0;
#pragma unroll
  for (int k=0;k<PER;k++){
    int i = base + k;
    int v = (i<n)? cnt[i] : 0;
    local[k] = v;
    s += v;
  }
  buf[t] = s;
  __syncthreads();
  for (int d2=1; d2<1024; d2<<=1){
    int tv = (t>=d2)? buf[t-d2] : 0;
    __syncthreads();
    buf[t] += tv;
    __syncthreads();
  }
  int run = buf[t] - s;   // exclusive prefix of this thread's chunk
#pragma unroll
  for (int k=0;k<PER;k++){
    int i = base + k;
    if (i < n){
      off[i] = run;
      int v = local[k];
      loop_attr[i] = (v>0) ? easum[i]/(float)v : 0.f;  // fill='mean'
      run += v;
    }
  }
  if (t == 1023) off[n] = buf[1023];
}

__global__ void edge_fill_kernel(const int* __restrict__ ei, const float* __restrict__ ea,
                                 const int* __restrict__ off, int* __restrict__ fill,
                                 int* __restrict__ csr_src, float* __restrict__ csr_ea, int E){
  int e = blockIdx.x*256 + threadIdx.x;
  if (e >= E) return;
  int dst = ei[E + e];
  int pos = off[dst] + atomicAdd(&fill[dst], 1);
  csr_src[pos] = ei[e];
  csr_ea[pos]  = ea[e];
}

// ---------------- conversions ----------------
// transpose: W[K,N] f32 -> Wt[N,K] f16
__global__ void wt_f16_kernel(const float* __restrict__ W, int K, int N,
                              unsigned short* __restrict__ Wt){
  __shared__ float tile[32][33];
  int k0 = blockIdx.x*32, n0 = blockIdx.y*32;
  int tx = threadIdx.x & 31, ty = threadIdx.x >> 5; // 32 x 8
  for (int r=ty; r<32; r+=8) tile[r][tx] = W[(size_t)(k0+r)*N + n0+tx];
  __syncthreads();
  for (int r=ty; r<32; r+=8){
    float w = tile[tx][r];               // = W[k0+tx][n0+r]
    Wt[(size_t)(n0+r)*K + k0+tx] = f2hu(w);
  }
}

// ---------------- cross-attention (rank-1 collapsed) ----------------
__global__ void kv_kernel(const float* __restrict__ x,
                          const float* __restrict__ kw, const float* __restrict__ kb,
                          const float* __restrict__ vw, const float* __restrict__ vb,
                          float* __restrict__ Kv, float* __restrict__ Vv){
  int j = threadIdx.x; // 256
  float ka = kb[j], va = vb[j];
  for (int k=0;k<200;k++){
    float m = x[1280+k];
    ka = fmaf(m, kw[k*256+j], ka);
    va = fmaf(m, vw[k*256+j], va);
  }
  Kv[j]=ka; Vv[j]=va;
}

// v2: qK via wave-per-row (coalesced float4 lane loads + shuffle reduce, 20 blocks);
//     Vo via thread-per-column (coalesced, 5 blocks). 25 blocks total.
__global__ void qkvo_kernel(const float* __restrict__ qw, const float* __restrict__ ow,
                            const float* __restrict__ Kv, const float* __restrict__ Vv,
                            float* __restrict__ qK, float* __restrict__ Vo){
  int b = blockIdx.x;
  if (b < 20){
    int wv = threadIdx.x>>6, lane = threadIdx.x&63;
    float4 k4 = ((const float4*)Kv)[lane];
    int w0 = b*4 + wv;                 // 80 waves
    for (int r = w0; r < 1280; r += 80){
      float4 q = *(const float4*)(qw + (size_t)r*256 + lane*4);
      float v = q.x*k4.x + q.y*k4.y + q.z*k4.z + q.w*k4.w;
      v = wsum(v);
      if (lane==0) qK[r] = v;
    }
  } else {
    int j = (b-20)*256 + threadIdx.x;  // < 1280
    float a=0;
    for (int i=0;i<256;i++) a = fmaf(Vv[i], ow[(size_t)i*1280+j], a);
    Vo[j]=a;
  }
}

// v2: i-split partials (grid 4 x 10), atomicAdd combine. Was 4 blocks reading
// 5.2 MB with a serial 1280-loop (hidden ~20-40us hog); now 40 blocks.
__global__ void obw_kernel(const float* __restrict__ ob, const float* __restrict__ Vo,
                           const float* __restrict__ W, float* __restrict__ obW, float* __restrict__ VoW){
  int j = blockIdx.x*256 + threadIdx.x; // < 1024
  int i0 = blockIdx.y*128;
  float a=0,b=0;
  for (int i=i0;i<i0+128;i++){
    float w = W[(size_t)i*1024+j];
    a = fmaf(ob[i], w, a);
    b = fmaf(Vo[i], w, b);
  }
  atomicAdd(&obW[j], a);
  atomicAdd(&VoW[j], b);
}

// FUSED x f32 -> f16 conversion + scores dot (reads x once, writes Af + scores).
__launch_bounds__(256)
__global__ void xh_scores_kernel(const float* __restrict__ x, const float* __restrict__ qK,
                                 unsigned short* __restrict__ xh, float* __restrict__ scores, int n){
  __shared__ float qs[1280];
  int t = threadIdx.x;
  for (int i=t;i<1280;i+=256) qs[i]=qK[i];
  __syncthreads();
  int wid = t>>6, lane = t&63;
  int node = blockIdx.x*4 + wid;
  if (node >= n) return;
  const float* xr = x + (size_t)node*XROW;
  unsigned short* orow = xh + (size_t)node*1280;
  float acc = 0.f;
#pragma unroll
  for (int it=0; it<5; it++){
    int c4 = it*64 + lane;           // < 320
    float4 v = *(const float4*)(xr + c4*4);
    ushort4 o;
    o.x = f2hu(v.x); o.y = f2hu(v.y); o.z = f2hu(v.z); o.w = f2hu(v.w);
    *(ushort4*)(orow + c4*4) = o;
    acc = fmaf(v.x, qs[c4*4+0], acc);
    acc = fmaf(v.y, qs[c4*4+1], acc);
    acc = fmaf(v.z, qs[c4*4+2], acc);
    acc = fmaf(v.w, qs[c4*4+3], acc);
  }
  acc = wsum(acc);
  if (lane==0) scores[node] = acc;
}

__launch_bounds__(1024)
__global__ void softmax_nodes(const float* __restrict__ scores, float* __restrict__ wts, int n){
  __shared__ float red[16];
  int t = threadIdx.x, lane=t&63, wid=t>>6;
  float m = -INFINITY;
  for (int i=t;i<n;i+=1024) m = fmaxf(m, scores[i]);
  m = wmax(m);
  if (lane==0) red[wid]=m;
  __syncthreads();
  if (t==0){ float r=red[0]; for (int k=1;k<16;k++) r=fmaxf(r,red[k]); red[0]=r; }
  __syncthreads();
  float M = red[0];
  __syncthreads();
  float z=0;
  for (int i=t;i<n;i+=1024) z += __expf((scores[i]-M)*(1.f/16.f));
  z = wsum(z);
  if (lane==0) red[wid]=z;
  __syncthreads();
  if (t==0){ float r=0; for (int k=0;k<16;k++) r+=red[k]; red[0]=r; }
  __syncthreads();
  float invZ = 1.f/red[0];
  for (int i=t;i<n;i+=1024) wts[i] = __expf((scores[i]-M)*(1.f/16.f))*invZ;
}

// ============ 256x256 f16 MFMA GEMM, COUNTED-vmcnt pipeline (v2) ============
// C[M,N] = A[M,K] @ B[N,K]^T. BK=64, 512 threads = 8 waves (2M x 4N), each wave
// owns 128x64 output (8x4 16x16 frags). LDS = 2 dbuf x (A 32K | B 32K) = 128 KB.
// v2 (fixes R3's drain-0 regression, per m218 counted-vs-drain0 = +38-73%):
//   per K-tile: issue ALL 8 next-tile global_load_lds -> other buffer, then
//   s_waitcnt vmcnt(8) (current tile landed; next tile's 8 stay in flight for
//   ~4 MFMA phases of cover), ONE barrier, then 4 phases of
//   {ds_read frags; lgkmcnt(0); setprio(1) 16 MFMA setprio(0); barrier}.
//   vmcnt never drains to 0 in the main loop.
// XOR swizzle: 16B-chunk col ^= (row&7) (measured SQ_LDS_BANK_CONFLICT = 0).
// N-tile(256) == one head -> epilogue writes als/ald DIRECTLY; (band0,nt0)
// also computes we[h].
__launch_bounds__(512,2)
__global__ void gemm256_f16(const unsigned short* __restrict__ A,
                            const unsigned short* __restrict__ B,
                            unsigned short* __restrict__ C, int M, int N, int K,
                            const float* __restrict__ addCol,   // obW or null
                            const float* __restrict__ vCol,     // VoW
                            const float* __restrict__ wRow,     // wts
                            const float* __restrict__ a_src,    // [N] flat
                            const float* __restrict__ a_dst,
                            float* __restrict__ als,            // [M*H] direct
                            float* __restrict__ ald,
                            const float* __restrict__ We,       // for we fold
                            const float* __restrict__ a_edge,
                            float* __restrict__ we)
{
  __shared__ short lds[2*32768];          // 128 KB: [buf][A 16384 | B 16384] shorts

  const int ntc = N >> 8;                 // 4 (1024) ; H == ntc
  const int sh  = (ntc==4)?2:((ntc==2)?1:0);
  const int g   = blockIdx.y >> sh;
  const int nt  = blockIdx.y & (ntc - 1);
  const int band = blockIdx.x + (g << 3);
  if (band * 256 >= M) return;

  const int t = threadIdx.x;
  const int w = t>>6, l = t&63;
  const int bm = band*256, bn = nt*256;
  const int wrh = w>>2;                   // A half (0/1): rows wrh*128..+127
  const int wcl = (w&3)*64;               // col band within tile
  const int q4 = l>>4, m16 = l&15;

  f32x4v acc[8][4];
#pragma unroll
  for (int i=0;i<8;i++)
#pragma unroll
    for (int j=0;j<4;j++) acc[i][j] = (f32x4v){0.f,0.f,0.f,0.f};

  // stage pointers: chunk p = (w*2+q)*64 + l within a 16KB half-tile (128 rows x 64 k)
  const unsigned short *pA00,*pA01,*pA10,*pA11,*pB00,*pB01,*pB10,*pB11;
  int lA00,lA01,lA10,lA11,lB00,lB01,lB10,lB11;
  {
#pragma unroll
    for (int half=0; half<2; half++){
#pragma unroll
      for (int q=0; q<2; q++){
        int p  = (w*2+q)*64 + l;
        int r  = p>>3, pc = p&7;
        int kc = (pc ^ (r&7))*8;
        int rowA = bm + half*128 + r; if (rowA > M-1) rowA = M-1;
        int rowB = bn + half*128 + r;
        const unsigned short* ap = A + (size_t)rowA*K + kc;
        const unsigned short* bp = B + (size_t)rowB*K + kc;
        int la = half*8192 + (w*2+q)*512;          // shorts
        int lb = 16384 + la;
        if (half==0 && q==0){ pA00=ap; pB00=bp; lA00=la; lB00=lb; }
        if (half==0 && q==1){ pA01=ap; pB01=bp; lA01=la; lB01=lb; }
        if (half==1 && q==0){ pA10=ap; pB10=bp; lA10=la; lB10=lb; }
        if (half==1 && q==1){ pA11=ap; pB11=bp; lA11=la; lB11=lb; }
      }
    }
  }

  const int nk = K >> 6;                  // 20 / 16

  // prologue: stage K-tile 0 -> buf0; NO drain (counted wait happens in-loop)
  {
    short* b0 = lds;
    async_copy16(b0 + lA00, pA00); async_copy16(b0 + lA01, pA01);
    async_copy16(b0 + lA10, pA10); async_copy16(b0 + lA11, pA11);
    async_copy16(b0 + lB00, pB00); async_copy16(b0 + lB01, pB01);
    async_copy16(b0 + lB10, pB10); async_copy16(b0 + lB11, pB11);
  }

  for (int kt = 0; kt < nk; ++kt){
    short* cur = lds + (kt&1)*32768;

    if (kt+1 < nk){
      // issue next tile's 8 loads -> other buffer; they stay in flight through
      // this tile's 4 MFMA phases (counted wait, T4)
      short* nxt = lds + ((kt+1)&1)*32768;
      const size_t kofs = (size_t)(kt+1)*64;
      async_copy16(nxt + lA00, pA00 + kofs); async_copy16(nxt + lA01, pA01 + kofs);
      async_copy16(nxt + lA10, pA10 + kofs); async_copy16(nxt + lA11, pA11 + kofs);
      async_copy16(nxt + lB00, pB00 + kofs); async_copy16(nxt + lB01, pB01 + kofs);
      async_copy16(nxt + lB10, pB10 + kofs); async_copy16(nxt + lB11, pB11 + kofs);
      asm volatile("s_waitcnt vmcnt(8)" ::: "memory");   // tile kt landed; kt+1 outstanding
    } else {
      asm volatile("s_waitcnt vmcnt(0)" ::: "memory");
    }
    __builtin_amdgcn_sched_barrier(0);
    __builtin_amdgcn_s_barrier();          // all waves' tile-kt data visible
    __builtin_amdgcn_sched_barrier(0);

    f16x8 bf[4];
#pragma unroll
    for (int ph = 0; ph < 4; ++ph){
      const int ks = ph >> 1, ih = ph & 1;
      const int c  = ks*4 + q4;
      f16x8 af[4];
#pragma unroll
      for (int ii=0; ii<4; ii++){
        int rl = (ih*4+ii)*16 + m16;                 // 0..127 within wave's A half
        af[ii] = *(const f16x8*)&cur[ wrh*8192 + rl*64 + ((c ^ (rl&7))*8) ];
      }
      if (ih == 0){
#pragma unroll
        for (int j=0;j<4;j++){
          int rb = wcl + j*16 + m16;                 // 0..255 within B region
          bf[j] = *(const f16x8*)&cur[ 16384 + rb*64 + ((c ^ (rb&7))*8) ];
        }
      }
      asm volatile("s_waitcnt lgkmcnt(0)" ::: "memory");
      __builtin_amdgcn_sched_barrier(0);
      __builtin_amdgcn_s_setprio(1);
#pragma unroll
      for (int ii=0; ii<4; ii++)
#pragma unroll
        for (int j=0; j<4; j++)
          acc[ih*4+ii][j] = __builtin_amdgcn_mfma_f32_16x16x32_f16(af[ii], bf[j], acc[ih*4+ii][j], 0,0,0);
      __builtin_amdgcn_s_setprio(0);
      __builtin_amdgcn_sched_barrier(0);
      __builtin_amdgcn_s_barrier();          // phase lockstep; ph3's doubles as
      __builtin_amdgcn_sched_barrier(0);     // read-done fence for buffer reuse
    }
  }

  // ---- epilogue: C store (+L0 fusion) + direct als/ald + we fold ----
  __syncthreads();
  float* sred = (float*)lds;              // [4 bands][256 rows]
  float* dred = sred + 1024;
  const int bandc = w & 3;

  float asv[4], adv[4];
#pragma unroll
  for (int j=0;j<4;j++){
    int n = bn + wcl + j*16 + m16;
    asv[j] = a_src[n];
    adv[j] = a_dst[n];
  }
#pragma unroll
  for (int i=0;i<8;i++){
#pragma unroll
    for (int r=0;r<4;r++){
      int rloc = wrh*128 + i*16 + q4*4 + r;
      int m = bm + rloc;
      float wrow = addCol ? wRow[m < M ? m : M-1] : 0.f;
      float vj[4];
#pragma unroll
      for (int j=0;j<4;j++){
        int n = bn + wcl + j*16 + m16;
        float v = acc[i][j][r];
        if (addCol) v += addCol[n] + wrow*vCol[n];
        vj[j] = v;
      }
      if (m < M){
        unsigned short* crow = C + (size_t)m*N;
#pragma unroll
        for (int j=0;j<4;j++) crow[bn + wcl + j*16 + m16] = f2hu(vj[j]);
      }
      float s = vj[0]*asv[0] + vj[1]*asv[1] + vj[2]*asv[2] + vj[3]*asv[3];
      float d = vj[0]*adv[0] + vj[1]*adv[1] + vj[2]*adv[2] + vj[3]*adv[3];
#pragma unroll
      for (int o=1;o<16;o<<=1){ s += __shfl_xor(s,o); d += __shfl_xor(d,o); }
      if (m16 == 0){
        sred[bandc*256 + rloc] = s;
        dred[bandc*256 + rloc] = d;
      }
    }
  }
  __syncthreads();
  if (t < 256){
    int m = bm + t;
    if (m < M){
      float s = sred[t] + sred[256+t] + sred[512+t] + sred[768+t];
      float d = dred[t] + dred[256+t] + dred[512+t] + dred[768+t];
      als[(size_t)m*ntc + nt] = s;
      ald[(size_t)m*ntc + nt] = d;
    }
  }
  // we fold (once per launch)
  if (band == 0 && nt == 0 && w < ntc){
    float4 a = ((const float4*)(We + w*256))[l];
    float4 b = ((const float4*)(a_edge + w*256))[l];
    float v = a.x*b.x + a.y*b.y + a.z*b.z + a.w*b.w;
    v = wsum(v);
    if (l==0) we[w]=v;
  }
}

// ---------------- 128x128 2-phase GEMM (kept for layer 2: N=256) ----------------
__launch_bounds__(256)
__global__ void gemm_f16(const unsigned short* __restrict__ A,
                         const unsigned short* __restrict__ B,
                         unsigned short* __restrict__ C, int M, int N, int K,
                         const float* __restrict__ addCol,   // obW or null
                         const float* __restrict__ vCol,     // VoW
                         const float* __restrict__ wRow,     // wts
                         const float* __restrict__ a_src,    // [N] flat
                         const float* __restrict__ a_dst,
                         float* __restrict__ alsp,           // [ntc][M] partials
                         float* __restrict__ aldp)
{
  __shared__ short lds[2*2*128*64];

  const int ntc = N >> 7;                 // N-tiles (pow2)
  const int sh  = __popc(ntc - 1);
  const int g   = blockIdx.y >> sh;
  const int nt  = blockIdx.y & (ntc - 1);
  const int band = blockIdx.x + (g << 3);
  if (band * 128 >= M) return;

  const int t = threadIdx.x;
  const int w = t>>6, l = t&63;
  const int bm = band*128, bn = nt*128;
  const int wr = (w>>1)*64, wc = (w&1)*64;
  const int half = w & 1;

  f32x4v acc[4][4];
#pragma unroll
  for (int i=0;i<4;i++)
#pragma unroll
    for (int j=0;j<4;j++) acc[i][j] = (f32x4v){0.f,0.f,0.f,0.f};

  const unsigned short* Ap[4]; const unsigned short* Bp[4];
  int ldsOff[4];
#pragma unroll
  for (int q=0;q<4;q++){
    int p  = (w*4+q)*64 + l;
    int r  = p>>3, pc = p&7;
    int kc = (pc ^ (r&7))*8;
    int rowA = bm + r; if (rowA > M-1) rowA = M-1;
    Ap[q] = A + (size_t)rowA*K + kc;
    Bp[q] = B + (size_t)(bn+r)*K + kc;
    ldsOff[q] = (w*4+q)*64*8;
  }

  const int nsteps = K >> 6;

#pragma unroll
  for (int q=0;q<4;q++) async_copy16(lds + ldsOff[q],        Ap[q]);
#pragma unroll
  for (int q=0;q<4;q++) async_copy16(lds + 8192 + ldsOff[q], Bp[q]);

  const int q4 = l>>4, m16 = l&15;

  for (int ks0=0; ks0<nsteps; ++ks0){
    short* curb = lds + (ks0&1)*16384;

    if (ks0+1 < nsteps){
      short* nxt = lds + ((ks0+1)&1)*16384;
      const int k0n = (ks0+1)*64;
#pragma unroll
      for (int q=0;q<4;q++) async_copy16(nxt + ldsOff[q],        Ap[q] + k0n);
#pragma unroll
      for (int q=0;q<4;q++) async_copy16(nxt + 8192 + ldsOff[q], Bp[q] + k0n);
      asm volatile("s_waitcnt vmcnt(8)" ::: "memory");
    } else {
      asm volatile("s_waitcnt vmcnt(0)" ::: "memory");
    }
    __builtin_amdgcn_sched_barrier(0);
    __builtin_amdgcn_s_barrier();
    __builtin_amdgcn_sched_barrier(0);

    __builtin_amdgcn_s_setprio(1);
#pragma unroll
    for (int ks=0; ks<2; ks++){
      f16x8 af[4], bf[4];
      const int c = ks*4 + q4;
#pragma unroll
      for (int i=0;i<4;i++){
        int ra = wr + i*16 + m16;
        af[i] = *(const f16x8*)&curb[ra*64 + ((c ^ (ra&7))*8)];
        int rb = wc + i*16 + m16;
        bf[i] = *(const f16x8*)&curb[8192 + rb*64 + ((c ^ (rb&7))*8)];
      }
#pragma unroll
      for (int i=0;i<4;i++)
#pragma unroll
        for (int j=0;j<4;j++)
          acc[i][j] = __builtin_amdgcn_mfma_f32_16x16x32_f16(af[i], bf[j], acc[i][j], 0,0,0);
    }
    __builtin_amdgcn_s_setprio(0);
    __builtin_amdgcn_sched_barrier(0);
    __builtin_amdgcn_s_barrier();
    __builtin_amdgcn_sched_barrier(0);
  }

  float* sred = (float*)lds;          // [2][128]
  float* dred = sred + 256;
  float asv[4], adv[4];
#pragma unroll
  for (int j=0;j<4;j++){
    int n = bn + wc + j*16 + m16;
    asv[j] = a_src[n];
    adv[j] = a_dst[n];
  }
#pragma unroll
  for (int i=0;i<4;i++){
#pragma unroll
    for (int r=0;r<4;r++){
      int rloc = wr + i*16 + q4*4 + r;
      int m = bm + rloc;
      float wrow = addCol ? wRow[m < M ? m : M-1] : 0.f;
      float vj[4];
#pragma unroll
      for (int j=0;j<4;j++){
        int n = bn + wc + j*16 + m16;
        float v = acc[i][j][r];
        if (addCol) v += addCol[n] + wrow*vCol[n];
        vj[j] = v;
      }
      if (m < M){
        unsigned short* crow = C + (size_t)m*N;
#pragma unroll
        for (int j=0;j<4;j++) crow[bn + wc + j*16 + m16] = f2hu(vj[j]);
      }
      float s = vj[0]*asv[0] + vj[1]*asv[1] + vj[2]*asv[2] + vj[3]*asv[3];
      float d = vj[0]*adv[0] + vj[1]*adv[1] + vj[2]*adv[2] + vj[3]*adv[3];
#pragma unroll
      for (int o=1;o<16;o<<=1){ s += __shfl_xor(s,o); d += __shfl_xor(d,o); }
      if (m16 == 0){
        sred[half*128 + rloc] = s;
        dred[half*128 + rloc] = d;
      }
    }
  }
  __syncthreads();
  if (t < 128){
    int m = bm + t;
    if (m < M){
      alsp[(size_t)nt*M + m] = sred[t] + sred[128+t];
      aldp[(size_t)nt*M + m] = dred[t] + dred[128+t];
    }
  }
}

// combine per-tile partials -> als/ald (layer 2 only); block 0 computes we[h].
__global__ void als_combine(const float* __restrict__ alsp, const float* __restrict__ aldp,
                            float* __restrict__ als, float* __restrict__ ald, int M, int H,
                            const float* __restrict__ We, const float* __restrict__ a_edge,
                            float* __restrict__ we){
  if (blockIdx.x == 0){
    int wid = threadIdx.x>>6, lane = threadIdx.x&63;
    if (wid < H){
      const float4* w4 = (const float4*)(We + wid*256);
      const float4* a4 = (const float4*)(a_edge + wid*256);
      float4 a = w4[lane], b = a4[lane];
      float v = a.x*b.x + a.y*b.y + a.z*b.z + a.w*b.w;
      v = wsum(v);
      if (lane==0) we[wid]=v;
    }
  }
  int idx = blockIdx.x*256 + threadIdx.x;
  if (idx >= M*H) return;
  int m = idx / H, hh = idx - m*H;
  als[idx] = alsp[(size_t)(2*hh)*M + m] + alsp[(size_t)(2*hh+1)*M + m];
  ald[idx] = aldp[(size_t)(2*hh)*M + m] + aldp[(size_t)(2*hh+1)*M + m];
}

// ---------------- fused alpha-softmax + aggregate + bias + LN + ReLU ----------------
template<int H>
__launch_bounds__(256)
__global__ void gat_agg_ln_wave(const unsigned short* __restrict__ hmat,
                           const float* __restrict__ als, const float* __restrict__ ald,
                           const int* __restrict__ off, const int* __restrict__ csr_src,
                           const float* __restrict__ csr_ea, const float* __restrict__ loop_attr,
                           const float* __restrict__ we,
                           const float* __restrict__ bias,
                           const float* __restrict__ ln_g, const float* __restrict__ ln_b,
                           float* __restrict__ outf, unsigned short* __restrict__ outb, int n)
{
  constexpr int OUT = 256*H;      // 1024 or 256
  constexpr int CPL = OUT/64;     // channels per lane: 16 or 4
  const int wv = threadIdx.x>>6, lane = threadIdx.x&63;
  const int i = blockIdx.x*4 + wv;
  __shared__ float wbuf_s[4][64*H];
  __shared__ int   sbuf_s[4][64];
  if (i >= n) return;
  float* wbuf = wbuf_s[wv];
  int*   sbuf = sbuf_s[wv];

  const int begin = off[i];
  const int deg   = off[i+1]-begin;
  const int S     = deg + 1;           // + self-loop

  float aldi[H], wei[H];
#pragma unroll
  for (int hh=0;hh<H;hh++){ aldi[hh]=ald[(size_t)i*H+hh]; wei[hh]=we[hh]; }
  const float lea = loop_attr[i];

  const int head = (lane*CPL) >> 8;
  const int c0   = lane*CPL;
  float acc[CPL];
#pragma unroll
  for (int c=0;c<CPL;c++) acc[c]=0.f;

  if (S <= 64){
    int src = i; float ev = lea;
    if (lane < deg){ src = csr_src[begin+lane]; ev = csr_ea[begin+lane]; }
    const bool act = lane < S;
    sbuf[lane] = src;

    if constexpr (CPL==16){
      u16x8 a0r0,a0r1,a1r0,a1r1;
      {
        const unsigned short* r0p = hmat + (size_t)sbuf[0]*OUT + c0;
        a0r0 = *(const u16x8*)r0p; a0r1 = *(const u16x8*)(r0p+8);
        a1r0 = a0r0; a1r1 = a0r1;
        if (S > 1){
          const unsigned short* r1p = hmat + (size_t)sbuf[1]*OUT + c0;
          a1r0 = *(const u16x8*)r1p; a1r1 = *(const u16x8*)(r1p+8);
        }
      }
      float a[H];
#pragma unroll
      for (int hh=0;hh<H;hh++){
        float v = als[(size_t)src*H+hh] + aldi[hh] + ev*wei[hh];
        a[hh] = v>0.f ? v : 0.2f*v;
      }
#pragma unroll
      for (int hh=0;hh<H;hh++){
        float M = wmax_all(act ? a[hh] : -INFINITY);
        float e = act ? __expf(a[hh]-M) : 0.f;
        float Z = wsum_all(e);
        wbuf[lane*H+hh] = e / (Z + 1e-16f);
      }
      int j = 0;
      for (; j+2<S; j+=2){
        u16x8 n0r0,n0r1,n1r0,n1r1;
        {
          const unsigned short* rp = hmat + (size_t)sbuf[j+2]*OUT + c0;
          n0r0 = *(const u16x8*)rp; n0r1 = *(const u16x8*)(rp+8);
          n1r0 = n0r0; n1r1 = n0r1;
          if (j+3 < S){
            const unsigned short* rq = hmat + (size_t)sbuf[j+3]*OUT + c0;
            n1r0 = *(const u16x8*)rq; n1r1 = *(const u16x8*)(rq+8);
          }
        }
        float w0 = wbuf[j*H+head], w1 = wbuf[(j+1)*H+head];
#pragma unroll
        for (int c=0;c<8;c++){
          acc[c]   = fmaf(w0, hu2f(a0r0[c]), acc[c]);
          acc[8+c] = fmaf(w0, hu2f(a0r1[c]), acc[8+c]);
        }
#pragma unroll
        for (int c=0;c<8;c++){
          acc[c]   = fmaf(w1, hu2f(a1r0[c]), acc[c]);
          acc[8+c] = fmaf(w1, hu2f(a1r1[c]), acc[8+c]);
        }
        a0r0=n0r0; a0r1=n0r1; a1r0=n1r0; a1r1=n1r1;
      }
      {
        float w0 = wbuf[j*H+head];
#pragma unroll
        for (int c=0;c<8;c++){
          acc[c]   = fmaf(w0, hu2f(a0r0[c]), acc[c]);
          acc[8+c] = fmaf(w0, hu2f(a0r1[c]), acc[8+c]);
        }
        if (j+1 < S){
          float w1 = wbuf[(j+1)*H+head];
#pragma unroll
          for (int c=0;c<8;c++){
            acc[c]   = fmaf(w1, hu2f(a1r0[c]), acc[c]);
            acc[8+c] = fmaf(w1, hu2f(a1r1[c]), acc[8+c]);
          }
        }
      }
    } else {
      ushort4 a0, a1;
      {
        a0 = *(const ushort4*)(hmat + (size_t)sbuf[0]*OUT + c0);
        a1 = a0;
        if (S > 1) a1 = *(const ushort4*)(hmat + (size_t)sbuf[1]*OUT + c0);
      }
      float a[H];
#pragma unroll
      for (int hh=0;hh<H;hh++){
        float v = als[(size_t)src*H+hh] + aldi[hh] + ev*wei[hh];
        a[hh] = v>0.f ? v : 0.2f*v;
      }
#pragma unroll
      for (int hh=0;hh<H;hh++){
        float M = wmax_all(act ? a[hh] : -INFINITY);
        float e = act ? __expf(a[hh]-M) : 0.f;
        float Z = wsum_all(e);
        wbuf[lane*H+hh] = e / (Z + 1e-16f);
      }
      int j = 0;
      for (; j+2<S; j+=2){
        ushort4 n0, n1;
        n0 = *(const ushort4*)(hmat + (size_t)sbuf[j+2]*OUT + c0);
        n1 = n0;
        if (j+3 < S) n1 = *(const ushort4*)(hmat + (size_t)sbuf[j+3]*OUT + c0);
        float w0 = wbuf[j*H+head], w1 = wbuf[(j+1)*H+head];
        acc[0]=fmaf(w0,hu2f(a0.x),acc[0]); acc[1]=fmaf(w0,hu2f(a0.y),acc[1]);
        acc[2]=fmaf(w0,hu2f(a0.z),acc[2]); acc[3]=fmaf(w0,hu2f(a0.w),acc[3]);
        acc[0]=fmaf(w1,hu2f(a1.x),acc[0]); acc[1]=fmaf(w1,hu2f(a1.y),acc[1]);
        acc[2]=fmaf(w1,hu2f(a1.z),acc[2]); acc[3]=fmaf(w1,hu2f(a1.w),acc[3]);
        a0=n0; a1=n1;
      }
      {
        float w0 = wbuf[j*H+head];
        acc[0]=fmaf(w0,hu2f(a0.x),acc[0]); acc[1]=fmaf(w0,hu2f(a0.y),acc[1]);
        acc[2]=fmaf(w0,hu2f(a0.z),acc[2]); acc[3]=fmaf(w0,hu2f(a0.w),acc[3]);
        if (j+1 < S){
          float w1 = wbuf[(j+1)*H+head];
          acc[0]=fmaf(w1,hu2f(a1.x),acc[0]); acc[1]=fmaf(w1,hu2f(a1.y),acc[1]);
          acc[2]=fmaf(w1,hu2f(a1.z),acc[2]); acc[3]=fmaf(w1,hu2f(a1.w),acc[3]);
        }
      }
    }
  } else {
    float rm[H];
#pragma unroll
    for (int hh=0;hh<H;hh++) rm[hh] = -INFINITY;
    for (int s=lane; s<S; s+=64){
      int src = (s<deg)? csr_src[begin+s] : i;
      float ev = (s<deg)? csr_ea[begin+s] : lea;
#pragma unroll
      for (int hh=0;hh<H;hh++){
        float v = als[(size_t)src*H+hh] + aldi[hh] + ev*wei[hh];
        v = v>0.f? v : 0.2f*v;
        rm[hh] = fmaxf(rm[hh], v);
      }
    }
    float M[H], es[H];
#pragma unroll
    for (int hh=0;hh<H;hh++){ M[hh]=wmax_all(rm[hh]); es[hh]=0.f; }
    for (int s=lane; s<S; s+=64){
      int src = (s<deg)? csr_src[begin+s] : i;
      float ev = (s<deg)? csr_ea[begin+s] : lea;
#pragma unroll
      for (int hh=0;hh<H;hh++){
        float v = als[(size_t)src*H+hh] + aldi[hh] + ev*wei[hh];
        v = v>0.f? v : 0.2f*v;
        es[hh] += __expf(v - M[hh]);
      }
    }
    float invZ[H];
#pragma unroll
    for (int hh=0;hh<H;hh++) invZ[hh] = 1.f/(wsum_all(es[hh]) + 1e-16f);
    for (int cb=0; cb<S; cb+=64){
      int m = min(64, S-cb);
      int s = cb + lane;
      if (s < S){
        int src = (s<deg)? csr_src[begin+s] : i;
        float ev = (s<deg)? csr_ea[begin+s] : lea;
        sbuf[lane] = src;
#pragma unroll
        for (int hh=0;hh<H;hh++){
          float v = als[(size_t)src*H+hh] + aldi[hh] + ev*wei[hh];
          v = v>0.f? v : 0.2f*v;
          wbuf[lane*H+hh] = __expf(v - M[hh]) * invZ[hh];
        }
      }
      for (int j=0;j<m;j++){
        int sj = sbuf[j];
        float wj = wbuf[j*H+head];
        const unsigned short* row = hmat + (size_t)sj*OUT + c0;
        if constexpr (CPL==16){
          u16x8 r0 = *(const u16x8*)(row);
          u16x8 r1 = *(const u16x8*)(row+8);
#pragma unroll
          for (int c=0;c<8;c++){
            acc[c]   = fmaf(wj, hu2f(r0[c]), acc[c]);
            acc[8+c] = fmaf(wj, hu2f(r1[c]), acc[8+c]);
          }
        } else {
          ushort4 r = *(const ushort4*)(row);
          acc[0]=fmaf(wj,hu2f(r.x),acc[0]); acc[1]=fmaf(wj,hu2f(r.y),acc[1]);
          acc[2]=fmaf(wj,hu2f(r.z),acc[2]); acc[3]=fmaf(wj,hu2f(r.w),acc[3]);
        }
      }
    }
  }

  // ---- bias + LayerNorm + ReLU (wave-level) ----
  float vals[CPL];
  float ls=0.f;
#pragma unroll
  for (int c=0;c<CPL;c+=4){
    float4 b4 = *(const float4*)(bias + c0 + c);
    vals[c]=acc[c]+b4.x; vals[c+1]=acc[c+1]+b4.y; vals[c+2]=acc[c+2]+b4.z; vals[c+3]=acc[c+3]+b4.w;
    ls += vals[c]+vals[c+1]+vals[c+2]+vals[c+3];
  }
  float mu = wsum_all(ls) * (1.f/OUT);
  float lv=0.f;
#pragma unroll
  for (int c=0;c<CPL;c++){ float d=vals[c]-mu; lv += d*d; }
  float inv = rsqrtf(wsum_all(lv)*(1.f/OUT) + 1e-5f);

  if (outb){
    if constexpr (CPL==16){
#pragma unroll
      for (int c=0;c<CPL;c+=8){
        u16x8 o;
#pragma unroll
        for (int k=0;k<8;k++){
          float g = ln_g[c0+c+k], b = ln_b[c0+c+k];
          o[k] = f2hu(fmaxf((vals[c+k]-mu)*inv*g + b, 0.f));
        }
        *(u16x8*)(outb + (size_t)i*OUT + c0 + c) = o;
      }
    } else {
      ushort4 o;
      o.x = f2hu(fmaxf((vals[0]-mu)*inv*ln_g[c0+0] + ln_b[c0+0], 0.f));
      o.y = f2hu(fmaxf((vals[1]-mu)*inv*ln_g[c0+1] + ln_b[c0+1], 0.f));
      o.z = f2hu(fmaxf((vals[2]-mu)*inv*ln_g[c0+2] + ln_b[c0+2], 0.f));
      o.w = f2hu(fmaxf((vals[3]-mu)*inv*ln_g[c0+3] + ln_b[c0+3], 0.f));
      *(ushort4*)(outb + (size_t)i*OUT + c0) = o;
    }
  } else {
#pragma unroll
    for (int c=0;c<CPL;c+=4){
      float4 g4 = *(const float4*)(ln_g + c0 + c);
      float4 b4 = *(const float4*)(ln_b + c0 + c);
      float4 o;
      o.x = fmaxf((vals[c+0]-mu)*inv*g4.x + b4.x, 0.f);
      o.y = fmaxf((vals[c+1]-mu)*inv*g4.y + b4.y, 0.f);
      o.z = fmaxf((vals[c+2]-mu)*inv*g4.z + b4.z, 0.f);
      o.w = fmaxf((vals[c+3]-mu)*inv*g4.w + b4.w, 0.f);
      *(float4*)(outf + (size_t)i*OUT + c0 + c) = o;
    }
  }
}

// ---------------- mean pool + classifier ----------------
__global__ void colsum_kernel(const float* __restrict__ h2, float* __restrict__ gsum, int n){
  int c = threadIdx.x; // 256
  float acc=0;
  for (int i=blockIdx.x;i<n;i+=gridDim.x) acc += h2[(size_t)i*256 + c];
  atomicAdd(&gsum[c], acc);
}

__launch_bounds__(128)
__global__ void cls_kernel(const float* __restrict__ gsum,
                           const float* __restrict__ w1, const float* __restrict__ b1,
                           const float* __restrict__ w2, const float* __restrict__ b2,
                           float* __restrict__ outp){
  __shared__ float g[256];
  __shared__ float hid[128];
  int t = threadIdx.x;
  g[t]     = gsum[t]    *(1.f/N_NODES);
  g[t+128] = gsum[t+128]*(1.f/N_NODES);
  __syncthreads();
  float a = b1[t];
  for (int c=0;c<256;c++) a = fmaf(g[c], w1[c*128+t], a);
  hid[t] = fmaxf(a, 0.f);
  __syncthreads();
  if (t<2){
    float o = b2[t];
    for (int j=0;j<128;j++) o = fmaf(hid[j], w2[j*2+t], o);
    outp[t] = o;
  }
}

// ---------------- launch ----------------
extern "C" void kernel_launch(void* const* d_in, const int* in_sizes, int n_in,
                              void* d_out, int out_size, void* d_ws, size_t ws_size,
                              hipStream_t stream)
{
  const float* x      = (const float*)d_in[0];
  const int*   ei     = (const int*)  d_in[1];
  const float* ea     = (const float*)d_in[2];
  const float* ca_qw  = (const float*)d_in[3];
  const float* ca_kw  = (const float*)d_in[5];
  const float* ca_kb  = (const float*)d_in[6];
  const float* ca_vw  = (const float*)d_in[7];
  const float* ca_vb  = (const float*)d_in[8];
  const float* ca_ow  = (const float*)d_in[9];
  const float* ca_ob  = (const float*)d_in[10];
  const float* g0_w   = (const float*)d_in[11];
  const float* g0_ew  = (const float*)d_in[12];
  const float* g0_as  = (const float*)d_in[13];
  const float* g0_ad  = (const float*)d_in[14];
  const float* g0_ae  = (const float*)d_in[15];
  const float* g0_b   = (const float*)d_in[16];
  const float* ln0_g  = (const float*)d_in[17];
  const float* ln0_b  = (const float*)d_in[18];
  const float* g1_w   = (const float*)d_in[19];
  const float* g1_ew  = (const float*)d_in[20];
  const float* g1_as  = (const float*)d_in[21];
  const float* g1_ad  = (const float*)d_in[22];
  const float* g1_ae  = (const float*)d_in[23];
  const float* g1_b   = (const float*)d_in[24];
  const float* ln1_g  = (const float*)d_in[25];
  const float* ln1_b  = (const float*)d_in[26];
  const float* g2_w   = (const float*)d_in[27];
  const float* g2_ew  = (const float*)d_in[28];
  const float* g2_as  = (const float*)d_in[29];
  const float* g2_ad  = (const float*)d_in[30];
  const float* g2_ae  = (const float*)d_in[31];
  const float* g2_b   = (const float*)d_in[32];
  const float* ln2_g  = (const float*)d_in[33];
  const float* ln2_b  = (const float*)d_in[34];
  const float* cls_w1 = (const float*)d_in[35];
  const float* cls_b1 = (const float*)d_in[36];
  const float* cls_w2 = (const float*)d_in[37];
  const float* cls_b2 = (const float*)d_in[38];
  float* outp = (float*)d_out;

  const int N = N_NODES, E = N_EDGES;

  char* base = (char*)d_ws;
  size_t o = 0;
  auto alloc = [&](size_t bytes)->void*{
    void* p = base + o;
    o += (bytes + 255) & ~(size_t)255;
    return p;
  };
  unsigned short* hF   = (unsigned short*)alloc((size_t)N*1024*2); // GEMM output h (f16)
  unsigned short* Af   = (unsigned short*)alloc((size_t)N*1280*2); // f16 activations (x, then agg out)
  float*          h2   = (float*)         alloc((size_t)N*256*4);  // layer-2 agg out (f32)
  unsigned short* Wt   = (unsigned short*)alloc((size_t)1280*1024*2);
  float* alsp      = (float*)alloc((size_t)8*N*4);    // per-tile partials (layer 2)
  float* aldp      = (float*)alloc((size_t)8*N*4);
  float* als       = (float*)alloc((size_t)2*N*4*4);  // als | ald contiguous
  float* ald       = als + (size_t)N*4;
  float* scores    = (float*)alloc((size_t)N*4);
  float* wts       = (float*)alloc((size_t)N*4);
  int*   cnt       = (int*)  alloc((size_t)N*4);
  float* easum     = (float*)alloc((size_t)N*4);
  int*   off       = (int*)  alloc((size_t)(N+1)*4);
  int*   fill      = (int*)  alloc((size_t)N*4);
  int*   csr_src   = (int*)  alloc((size_t)E*4);
  float* csr_ea    = (float*)alloc((size_t)E*4);
  float* loop_attr = (float*)alloc((size_t)N*4);
  float* Kv        = (float*)alloc(256*4);
  float* Vv        = (float*)alloc(256*4);
  float* qK        = (float*)alloc(1280*4);
  float* Vo        = (float*)alloc(1280*4);
  float* obW       = (float*)alloc(1024*4);
  float* VoW       = (float*)alloc(1024*4);
  float* web       = (float*)alloc(16*4);
  float* gsum      = (float*)alloc(256*4);

  hipMemsetAsync(cnt,   0, (size_t)N*4, stream);
  hipMemsetAsync(easum, 0, (size_t)N*4, stream);
  hipMemsetAsync(fill,  0, (size_t)N*4, stream);
  hipMemsetAsync(gsum,  0, 256*4,       stream);
  hipMemsetAsync(obW,   0, 1024*4,      stream);
  hipMemsetAsync(VoW,   0, 1024*4,      stream);

  // ---- edge preprocessing (CSR by dst) ----
  int eblocks = (E + 255)/256;
  edge_count_kernel<<<eblocks,256,0,stream>>>(ei, ea, cnt, easum, E);
  scan_kernel<<<1,1024,0,stream>>>(cnt, easum, off, loop_attr, N);
  edge_fill_kernel<<<eblocks,256,0,stream>>>(ei, ea, off, fill, csr_src, csr_ea, E);

  // ---- cross-attention, rank-1 collapsed ----
  kv_kernel<<<1,256,0,stream>>>(x, ca_kw, ca_kb, ca_vw, ca_vb, Kv, Vv);
  qkvo_kernel<<<25,256,0,stream>>>(ca_qw, ca_ow, Kv, Vv, qK, Vo);
  xh_scores_kernel<<<(N+3)/4,256,0,stream>>>(x, qK, Af, scores, N);
  obw_kernel<<<dim3(4,10),256,0,stream>>>(ca_ob, Vo, g0_w, obW, VoW);
  softmax_nodes<<<1,1024,0,stream>>>(scores, wts, N);

  const int mTiles  = (N + 127)/128;        // 157 (layer-2 gemm)
  const int mGroups = (mTiles + 7)/8;       // 20
  const int mT256   = (N + 255)/256;        // 79
  const int mG256   = (mT256 + 7)/8;        // 10
  const int NB4 = (N + 3)/4;                // wave-per-node blocks

  // ---- layer 0 (256^2 counted-vmcnt GEMM, direct als + we fold) ----
  wt_f16_kernel<<<dim3(1280/32, 1024/32),256,0,stream>>>(g0_w, 1280, 1024, Wt);
  gemm256_f16<<<dim3(8, mG256*4),512,0,stream>>>(Af, Wt, hF, N, 1024, 1280, obW, VoW, wts,
                                                 g0_as, g0_ad, als, ald, g0_ew, g0_ae, web);
  gat_agg_ln_wave<4><<<NB4,256,0,stream>>>(hF, als, ald, off, csr_src, csr_ea, loop_attr,
                                           web, g0_b, ln0_g, ln0_b, nullptr, Af, N);

  // ---- layer 1 ----
  wt_f16_kernel<<<dim3(1024/32, 1024/32),256,0,stream>>>(g1_w, 1024, 1024, Wt);
  gemm256_f16<<<dim3(8, mG256*4),512,0,stream>>>(Af, Wt, hF, N, 1024, 1024, nullptr, nullptr, nullptr,
                                                 g1_as, g1_ad, als, ald, g1_ew, g1_ae, web);
  gat_agg_ln_wave<4><<<NB4,256,0,stream>>>(hF, als, ald, off, csr_src, csr_ea, loop_attr,
                                           web, g1_b, ln1_g, ln1_b, nullptr, Af, N);

  // ---- layer 2 (1 head, 256 out; 128^2 GEMM, better balance at N=256) ----
  wt_f16_kernel<<<dim3(1024/32, 256/32),256,0,stream>>>(g2_w, 1024, 256, Wt);
  gemm_f16<<<dim3(8, mGroups*2),256,0,stream>>>(Af, Wt, hF, N, 256, 1024, nullptr, nullptr, nullptr,
                                                g2_as, g2_ad, alsp, aldp);
  als_combine<<<(N+255)/256,256,0,stream>>>(alsp, aldp, als, ald, N, 1, g2_ew, g2_ae, web);
  gat_agg_ln_wave<1><<<NB4,256,0,stream>>>(hF, als, ald, off, csr_src, csr_ea, loop_attr,
                                           web, g2_b, ln2_g, ln2_b, h2, nullptr, N);

  // ---- mean pool + classifier ----
  colsum_kernel<<<256,256,0,stream>>>(h2, gsum, N);
  cls_kernel<<<1,128,0,stream>>>(gsum, cls_w1, cls_b1, cls_w2, cls_b2, outp);

  (void)in_sizes; (void)n_in; (void)out_size; (void)ws_size;
}

// Round 5
// 800.739 us; speedup vs baseline: 1.1255x; 1.0724x over previous
//
#include <hip/hip_runtime.h>
#include <hip/hip_bf16.h>
#include <math.h>

#define N_NODES 20000
#define N_EDGES 200000
#define XROW    1480   // EMB + MD

typedef __attribute__((ext_vector_type(8))) _Float16 f16x8;
typedef __attribute__((ext_vector_type(8))) unsigned short u16x8;
typedef __attribute__((ext_vector_type(4))) float f32x4v;

// ---------------- reduction helpers ----------------
__device__ __forceinline__ float wsum(float v){
#pragma unroll
  for (int o=32;o>0;o>>=1) v += __shfl_down(v,o);
  return v;
}
__device__ __forceinline__ float wmax(float v){
#pragma unroll
  for (int o=32;o>0;o>>=1) v = fmaxf(v,__shfl_down(v,o));
  return v;
}
// butterfly: result in ALL lanes
__device__ __forceinline__ float wsum_all(float v){
#pragma unroll
  for (int o=32;o>0;o>>=1) v += __shfl_xor(v,o);
  return v;
}
__device__ __forceinline__ float wmax_all(float v){
#pragma unroll
  for (int o=32;o>0;o>>=1) v = fmaxf(v,__shfl_xor(v,o));
  return v;
}

__device__ __forceinline__ unsigned short f2hu(float f){
  _Float16 h = (_Float16)f;
  return __builtin_bit_cast(unsigned short, h);
}
__device__ __forceinline__ float hu2f(unsigned short u){
  return (float)__builtin_bit_cast(_Float16, u);
}

__device__ __forceinline__ void async_copy16(void* lds, const void* g){
  __builtin_amdgcn_global_load_lds((const __attribute__((address_space(1))) void*)g,
                                   (__attribute__((address_space(3))) void*)lds, 16, 0, 0);
}

// ---------------- edge preprocessing (once, reused 3 layers) ----------------
__global__ void edge_count_kernel(const int* __restrict__ ei, const float* __restrict__ ea,
                                  int* __restrict__ cnt, float* __restrict__ easum, int E){
  int e = blockIdx.x*256 + threadIdx.x;
  if (e >= E) return;
  int dst = ei[E + e];
  atomicAdd(&cnt[dst], 1);
  atomicAdd(&easum[dst], ea[e]);
}

// thread-serial chunk of 20 + single 1024 Kogge-Stone scan
__launch_bounds__(1024)
__global__ void scan_kernel(const int* __restrict__ cnt, const float* __restrict__ easum,
                            int* __restrict__ off, float* __restrict__ loop_attr, int n){
  __shared__ int buf[1024];
  const int PER = (N_NODES + 1023)/1024;   // 20
  int t = threadIdx.x;
  int base = t*PER;
  int local[PER];
  int s = 0;
#pragma unroll
  for (int k=0;k<PER;k++){
    int i = base + k;
    int v = (i<n)? cnt[i] : 0;
    local[k] = v;
    s += v;
  }
  buf[t] = s;
  __syncthreads();
  for (int d2=1; d2<1024; d2<<=1){
    int tv = (t>=d2)? buf[t-d2] : 0;
    __syncthreads();
    buf[t] += tv;
    __syncthreads();
  }
  int run = buf[t] - s;   // exclusive prefix of this thread's chunk
#pragma unroll
  for (int k=0;k<PER;k++){
    int i = base + k;
    if (i < n){
      off[i] = run;
      int v = local[k];
      loop_attr[i] = (v>0) ? easum[i]/(float)v : 0.f;  // fill='mean'
      run += v;
    }
  }
  if (t == 1023) off[n] = buf[1023];
}

__global__ void edge_fill_kernel(const int* __restrict__ ei, const float* __restrict__ ea,
                                 const int* __restrict__ off, int* __restrict__ fill,
                                 int* __restrict__ csr_src, float* __restrict__ csr_ea, int E){
  int e = blockIdx.x*256 + threadIdx.x;
  if (e >= E) return;
  int dst = ei[E + e];
  int pos = off[dst] + atomicAdd(&fill[dst], 1);
  csr_src[pos] = ei[e];
  csr_ea[pos]  = ea[e];
}

// ---------------- conversions ----------------
// transpose: W[K,N] f32 -> Wt[N,K] f16
__global__ void wt_f16_kernel(const float* __restrict__ W, int K, int N,
                              unsigned short* __restrict__ Wt){
  __shared__ float tile[32][33];
  int k0 = blockIdx.x*32, n0 = blockIdx.y*32;
  int tx = threadIdx.x & 31, ty = threadIdx.x >> 5; // 32 x 8
  for (int r=ty; r<32; r+=8) tile[r][tx] = W[(size_t)(k0+r)*N + n0+tx];
  __syncthreads();
  for (int r=ty; r<32; r+=8){
    float w = tile[tx][r];               // = W[k0+tx][n0+r]
    Wt[(size_t)(n0+r)*K + k0+tx] = f2hu(w);
  }
}

// ---------------- cross-attention (rank-1 collapsed) ----------------
__global__ void kv_kernel(const float* __restrict__ x,
                          const float* __restrict__ kw, const float* __restrict__ kb,
                          const float* __restrict__ vw, const float* __restrict__ vb,
                          float* __restrict__ Kv, float* __restrict__ Vv){
  int j = threadIdx.x; // 256
  float ka = kb[j], va = vb[j];
  for (int k=0;k<200;k++){
    float m = x[1280+k];
    ka = fmaf(m, kw[k*256+j], ka);
    va = fmaf(m, vw[k*256+j], va);
  }
  Kv[j]=ka; Vv[j]=va;
}

// qK via wave-per-row (coalesced float4 lane loads + shuffle reduce, 20 blocks);
// Vo via thread-per-column (coalesced, 5 blocks). 25 blocks total.
__global__ void qkvo_kernel(const float* __restrict__ qw, const float* __restrict__ ow,
                            const float* __restrict__ Kv, const float* __restrict__ Vv,
                            float* __restrict__ qK, float* __restrict__ Vo){
  int b = blockIdx.x;
  if (b < 20){
    int wv = threadIdx.x>>6, lane = threadIdx.x&63;
    float4 k4 = ((const float4*)Kv)[lane];
    int w0 = b*4 + wv;                 // 80 waves
    for (int r = w0; r < 1280; r += 80){
      float4 q = *(const float4*)(qw + (size_t)r*256 + lane*4);
      float v = q.x*k4.x + q.y*k4.y + q.z*k4.z + q.w*k4.w;
      v = wsum(v);
      if (lane==0) qK[r] = v;
    }
  } else {
    int j = (b-20)*256 + threadIdx.x;  // < 1280
    float a=0;
    for (int i=0;i<256;i++) a = fmaf(Vv[i], ow[(size_t)i*1280+j], a);
    Vo[j]=a;
  }
}

// i-split partials (grid 4 x 10), atomicAdd combine. (was a hidden 4-block hog)
__global__ void obw_kernel(const float* __restrict__ ob, const float* __restrict__ Vo,
                           const float* __restrict__ W, float* __restrict__ obW, float* __restrict__ VoW){
  int j = blockIdx.x*256 + threadIdx.x; // < 1024
  int i0 = blockIdx.y*128;
  float a=0,b=0;
  for (int i=i0;i<i0+128;i++){
    float w = W[(size_t)i*1024+j];
    a = fmaf(ob[i], w, a);
    b = fmaf(Vo[i], w, b);
  }
  atomicAdd(&obW[j], a);
  atomicAdd(&VoW[j], b);
}

// FUSED x f32 -> f16 conversion + scores dot (reads x once, writes Af + scores).
__launch_bounds__(256)
__global__ void xh_scores_kernel(const float* __restrict__ x, const float* __restrict__ qK,
                                 unsigned short* __restrict__ xh, float* __restrict__ scores, int n){
  __shared__ float qs[1280];
  int t = threadIdx.x;
  for (int i=t;i<1280;i+=256) qs[i]=qK[i];
  __syncthreads();
  int wid = t>>6, lane = t&63;
  int node = blockIdx.x*4 + wid;
  if (node >= n) return;
  const float* xr = x + (size_t)node*XROW;
  unsigned short* orow = xh + (size_t)node*1280;
  float acc = 0.f;
#pragma unroll
  for (int it=0; it<5; it++){
    int c4 = it*64 + lane;           // < 320
    float4 v = *(const float4*)(xr + c4*4);
    ushort4 o;
    o.x = f2hu(v.x); o.y = f2hu(v.y); o.z = f2hu(v.z); o.w = f2hu(v.w);
    *(ushort4*)(orow + c4*4) = o;
    acc = fmaf(v.x, qs[c4*4+0], acc);
    acc = fmaf(v.y, qs[c4*4+1], acc);
    acc = fmaf(v.z, qs[c4*4+2], acc);
    acc = fmaf(v.w, qs[c4*4+3], acc);
  }
  acc = wsum(acc);
  if (lane==0) scores[node] = acc;
}

__launch_bounds__(1024)
__global__ void softmax_nodes(const float* __restrict__ scores, float* __restrict__ wts, int n){
  __shared__ float red[16];
  int t = threadIdx.x, lane=t&63, wid=t>>6;
  float m = -INFINITY;
  for (int i=t;i<n;i+=1024) m = fmaxf(m, scores[i]);
  m = wmax(m);
  if (lane==0) red[wid]=m;
  __syncthreads();
  if (t==0){ float r=red[0]; for (int k=1;k<16;k++) r=fmaxf(r,red[k]); red[0]=r; }
  __syncthreads();
  float M = red[0];
  __syncthreads();
  float z=0;
  for (int i=t;i<n;i+=1024) z += __expf((scores[i]-M)*(1.f/16.f));
  z = wsum(z);
  if (lane==0) red[wid]=z;
  __syncthreads();
  if (t==0){ float r=0; for (int k=0;k<16;k++) r+=red[k]; red[0]=r; }
  __syncthreads();
  float invZ = 1.f/red[0];
  for (int i=t;i<n;i+=1024) wts[i] = __expf((scores[i]-M)*(1.f/16.f))*invZ;
}

// ---------------- f16 MFMA GEMM (TN): C[M,N] = A[M,K] @ B[N,K]^T ----------------
// 128x128 tile, BK=64, 256 threads (4 waves, 2x2 of 64x64), 16x16x32 f16 MFMA.
// DOUBLE-BUFFERED LDS + COUNTED vmcnt pipeline. Measured best (557 TF @ this
// shape = the 2-phase-structure ceiling; 256^2 ports regressed twice -> keep).
__launch_bounds__(256)
__global__ void gemm_f16(const unsigned short* __restrict__ A,
                         const unsigned short* __restrict__ B,
                         unsigned short* __restrict__ C, int M, int N, int K,
                         const float* __restrict__ addCol,   // obW or null
                         const float* __restrict__ vCol,     // VoW
                         const float* __restrict__ wRow,     // wts
                         const float* __restrict__ a_src,    // [N] flat
                         const float* __restrict__ a_dst,
                         float* __restrict__ alsp,           // [ntc][M] partials
                         float* __restrict__ aldp)
{
  __shared__ short lds[2*2*128*64];

  const int ntc = N >> 7;                 // N-tiles (pow2: 8 or 2)
  const int sh  = __popc(ntc - 1);
  const int g   = blockIdx.y >> sh;
  const int nt  = blockIdx.y & (ntc - 1);
  const int band = blockIdx.x + (g << 3); // bx + 8*g
  if (band * 128 >= M) return;

  const int t = threadIdx.x;
  const int w = t>>6, l = t&63;
  const int bm = band*128, bn = nt*128;
  const int wr = (w>>1)*64, wc = (w&1)*64;
  const int half = w & 1;                 // which 64-col half of the tile

  f32x4v acc[4][4];
#pragma unroll
  for (int i=0;i<4;i++)
#pragma unroll
    for (int j=0;j<4;j++) acc[i][j] = (f32x4v){0.f,0.f,0.f,0.f};

  const unsigned short* Ap[4]; const unsigned short* Bp[4];
  int ldsOff[4];
#pragma unroll
  for (int q=0;q<4;q++){
    int p  = (w*4+q)*64 + l;       // phys 16B-chunk
    int r  = p>>3, pc = p&7;
    int kc = (pc ^ (r&7))*8;       // logical k element offset (XOR swizzle)
    int rowA = bm + r; if (rowA > M-1) rowA = M-1;
    Ap[q] = A + (size_t)rowA*K + kc;
    Bp[q] = B + (size_t)(bn+r)*K + kc;
    ldsOff[q] = (w*4+q)*64*8;      // shorts (wave-uniform base; lane spreads x16B)
  }

  const int nsteps = K >> 6;              // 20 / 16 / 16

  // prologue: stage tile 0 -> buffer 0 (8 loads/wave in flight)
#pragma unroll
  for (int q=0;q<4;q++) async_copy16(lds + ldsOff[q],        Ap[q]);
#pragma unroll
  for (int q=0;q<4;q++) async_copy16(lds + 8192 + ldsOff[q], Bp[q]);

  const int q4 = l>>4, m16 = l&15;

  for (int ks0=0; ks0<nsteps; ++ks0){
    short* curb = lds + (ks0&1)*16384;

    if (ks0+1 < nsteps){
      // issue next tile's stage -> other buffer; stays in flight across barriers
      short* nxt = lds + ((ks0+1)&1)*16384;
      const int k0n = (ks0+1)*64;
#pragma unroll
      for (int q=0;q<4;q++) async_copy16(nxt + ldsOff[q],        Ap[q] + k0n);
#pragma unroll
      for (int q=0;q<4;q++) async_copy16(nxt + 8192 + ldsOff[q], Bp[q] + k0n);
      // wait only for CURRENT tile's 8 loads (8 newest = next tile remain out)
      asm volatile("s_waitcnt vmcnt(8)" ::: "memory");
    } else {
      asm volatile("s_waitcnt vmcnt(0)" ::: "memory");
    }
    __builtin_amdgcn_sched_barrier(0);
    __builtin_amdgcn_s_barrier();          // raw: no vmcnt(0) drain
    __builtin_amdgcn_sched_barrier(0);     // keep ds_reads below the barrier

    __builtin_amdgcn_s_setprio(1);
#pragma unroll
    for (int ks=0; ks<2; ks++){
      f16x8 af[4], bf[4];
      const int c = ks*4 + q4;
#pragma unroll
      for (int i=0;i<4;i++){
        int ra = wr + i*16 + m16;
        af[i] = *(const f16x8*)&curb[ra*64 + ((c ^ (ra&7))*8)];
        int rb = wc + i*16 + m16;
        bf[i] = *(const f16x8*)&curb[8192 + rb*64 + ((c ^ (rb&7))*8)];
      }
#pragma unroll
      for (int i=0;i<4;i++)
#pragma unroll
        for (int j=0;j<4;j++)
          acc[i][j] = __builtin_amdgcn_mfma_f32_16x16x32_f16(af[i], bf[j], acc[i][j], 0,0,0);
    }
    __builtin_amdgcn_s_setprio(0);
    __builtin_amdgcn_sched_barrier(0);     // all ds_reads of curb retired
    __builtin_amdgcn_s_barrier();          // now next iter may overwrite curb
    __builtin_amdgcn_sched_barrier(0);
  }

  // epilogue: C/D layout col = l&15, row = (l>>4)*4 + r ; f32 math then f16 store.
  float* sred = (float*)lds;          // [2][128]
  float* dred = sred + 256;           // [2][128]
  float asv[4], adv[4];
#pragma unroll
  for (int j=0;j<4;j++){
    int n = bn + wc + j*16 + m16;
    asv[j] = a_src[n];
    adv[j] = a_dst[n];
  }
#pragma unroll
  for (int i=0;i<4;i++){
#pragma unroll
    for (int r=0;r<4;r++){
      int rloc = wr + i*16 + q4*4 + r;
      int m = bm + rloc;
      float wrow = addCol ? wRow[m < M ? m : M-1] : 0.f;
      float vj[4];
#pragma unroll
      for (int j=0;j<4;j++){
        int n = bn + wc + j*16 + m16;
        float v = acc[i][j][r];
        if (addCol) v += addCol[n] + wrow*vCol[n];
        vj[j] = v;
      }
      if (m < M){
        unsigned short* crow = C + (size_t)m*N;
#pragma unroll
        for (int j=0;j<4;j++) crow[bn + wc + j*16 + m16] = f2hu(vj[j]);
      }
      float s = vj[0]*asv[0] + vj[1]*asv[1] + vj[2]*asv[2] + vj[3]*asv[3];
      float d = vj[0]*adv[0] + vj[1]*adv[1] + vj[2]*adv[2] + vj[3]*adv[3];
#pragma unroll
      for (int o=1;o<16;o<<=1){ s += __shfl_xor(s,o); d += __shfl_xor(d,o); }
      if (m16 == 0){
        sred[half*128 + rloc] = s;
        dred[half*128 + rloc] = d;
      }
    }
  }
  __syncthreads();
  if (t < 128){
    int m = bm + t;
    if (m < M){
      alsp[(size_t)nt*M + m] = sred[t] + sred[128+t];
      aldp[(size_t)nt*M + m] = dred[t] + dred[128+t];
    }
  }
}

// combine per-tile partials -> als/ald [m*H+hh]; each head spans 2 column tiles.
// Block 0 additionally computes we[h].
__global__ void als_combine(const float* __restrict__ alsp, const float* __restrict__ aldp,
                            float* __restrict__ als, float* __restrict__ ald, int M, int H,
                            const float* __restrict__ We, const float* __restrict__ a_edge,
                            float* __restrict__ we){
  if (blockIdx.x == 0){
    int wid = threadIdx.x>>6, lane = threadIdx.x&63;
    if (wid < H){
      const float4* w4 = (const float4*)(We + wid*256);
      const float4* a4 = (const float4*)(a_edge + wid*256);
      float4 a = w4[lane], b = a4[lane];
      float v = a.x*b.x + a.y*b.y + a.z*b.z + a.w*b.w;
      v = wsum(v);
      if (lane==0) we[wid]=v;
    }
  }
  int idx = blockIdx.x*256 + threadIdx.x;
  if (idx >= M*H) return;
  int m = idx / H, hh = idx - m*H;
  als[idx] = alsp[(size_t)(2*hh)*M + m] + alsp[(size_t)(2*hh+1)*M + m];
  ald[idx] = aldp[(size_t)(2*hh)*M + m] + aldp[(size_t)(2*hh+1)*M + m];
}

// ---------------- fused alpha-softmax + aggregate + bias + LN + ReLU ----------------
// ONE WAVE PER NODE (4 waves/block). Gather j-loop pairwise-unrolled with
// depth-1 prefetch.
template<int H>
__launch_bounds__(256)
__global__ void gat_agg_ln_wave(const unsigned short* __restrict__ hmat,
                           const float* __restrict__ als, const float* __restrict__ ald,
                           const int* __restrict__ off, const int* __restrict__ csr_src,
                           const float* __restrict__ csr_ea, const float* __restrict__ loop_attr,
                           const float* __restrict__ we,
                           const float* __restrict__ bias,
                           const float* __restrict__ ln_g, const float* __restrict__ ln_b,
                           float* __restrict__ outf, unsigned short* __restrict__ outb, int n)
{
  constexpr int OUT = 256*H;      // 1024 or 256
  constexpr int CPL = OUT/64;     // channels per lane: 16 or 4
  const int wv = threadIdx.x>>6, lane = threadIdx.x&63;
  const int i = blockIdx.x*4 + wv;
  __shared__ float wbuf_s[4][64*H];
  __shared__ int   sbuf_s[4][64];
  if (i >= n) return;
  float* wbuf = wbuf_s[wv];
  int*   sbuf = sbuf_s[wv];

  const int begin = off[i];
  const int deg   = off[i+1]-begin;
  const int S     = deg + 1;           // + self-loop

  float aldi[H], wei[H];
#pragma unroll
  for (int hh=0;hh<H;hh++){ aldi[hh]=ald[(size_t)i*H+hh]; wei[hh]=we[hh]; }
  const float lea = loop_attr[i];

  const int head = (lane*CPL) >> 8;
  const int c0   = lane*CPL;
  float acc[CPL];
#pragma unroll
  for (int c=0;c<CPL;c++) acc[c]=0.f;

  if (S <= 64){
    int src = i; float ev = lea;
    if (lane < deg){ src = csr_src[begin+lane]; ev = csr_ea[begin+lane]; }
    const bool act = lane < S;
    sbuf[lane] = src;

    if constexpr (CPL==16){
      u16x8 a0r0,a0r1,a1r0,a1r1;
      {
        const unsigned short* r0p = hmat + (size_t)sbuf[0]*OUT + c0;
        a0r0 = *(const u16x8*)r0p; a0r1 = *(const u16x8*)(r0p+8);
        a1r0 = a0r0; a1r1 = a0r1;
        if (S > 1){
          const unsigned short* r1p = hmat + (size_t)sbuf[1]*OUT + c0;
          a1r0 = *(const u16x8*)r1p; a1r1 = *(const u16x8*)(r1p+8);
        }
      }
      float a[H];
#pragma unroll
      for (int hh=0;hh<H;hh++){
        float v = als[(size_t)src*H+hh] + aldi[hh] + ev*wei[hh];
        a[hh] = v>0.f ? v : 0.2f*v;
      }
#pragma unroll
      for (int hh=0;hh<H;hh++){
        float M = wmax_all(act ? a[hh] : -INFINITY);
        float e = act ? __expf(a[hh]-M) : 0.f;
        float Z = wsum_all(e);
        wbuf[lane*H+hh] = e / (Z + 1e-16f);
      }
      int j = 0;
      for (; j+2<S; j+=2){
        u16x8 n0r0,n0r1,n1r0,n1r1;
        {
          const unsigned short* rp = hmat + (size_t)sbuf[j+2]*OUT + c0;
          n0r0 = *(const u16x8*)rp; n0r1 = *(const u16x8*)(rp+8);
          n1r0 = n0r0; n1r1 = n0r1;
          if (j+3 < S){
            const unsigned short* rq = hmat + (size_t)sbuf[j+3]*OUT + c0;
            n1r0 = *(const u16x8*)rq; n1r1 = *(const u16x8*)(rq+8);
          }
        }
        float w0 = wbuf[j*H+head], w1 = wbuf[(j+1)*H+head];
#pragma unroll
        for (int c=0;c<8;c++){
          acc[c]   = fmaf(w0, hu2f(a0r0[c]), acc[c]);
          acc[8+c] = fmaf(w0, hu2f(a0r1[c]), acc[8+c]);
        }
#pragma unroll
        for (int c=0;c<8;c++){
          acc[c]   = fmaf(w1, hu2f(a1r0[c]), acc[c]);
          acc[8+c] = fmaf(w1, hu2f(a1r1[c]), acc[8+c]);
        }
        a0r0=n0r0; a0r1=n0r1; a1r0=n1r0; a1r1=n1r1;
      }
      {
        float w0 = wbuf[j*H+head];
#pragma unroll
        for (int c=0;c<8;c++){
          acc[c]   = fmaf(w0, hu2f(a0r0[c]), acc[c]);
          acc[8+c] = fmaf(w0, hu2f(a0r1[c]), acc[8+c]);
        }
        if (j+1 < S){
          float w1 = wbuf[(j+1)*H+head];
#pragma unroll
          for (int c=0;c<8;c++){
            acc[c]   = fmaf(w1, hu2f(a1r0[c]), acc[c]);
            acc[8+c] = fmaf(w1, hu2f(a1r1[c]), acc[8+c]);
          }
        }
      }
    } else {
      ushort4 a0, a1;
      {
        a0 = *(const ushort4*)(hmat + (size_t)sbuf[0]*OUT + c0);
        a1 = a0;
        if (S > 1) a1 = *(const ushort4*)(hmat + (size_t)sbuf[1]*OUT + c0);
      }
      float a[H];
#pragma unroll
      for (int hh=0;hh<H;hh++){
        float v = als[(size_t)src*H+hh] + aldi[hh] + ev*wei[hh];
        a[hh] = v>0.f ? v : 0.2f*v;
      }
#pragma unroll
      for (int hh=0;hh<H;hh++){
        float M = wmax_all(act ? a[hh] : -INFINITY);
        float e = act ? __expf(a[hh]-M) : 0.f;
        float Z = wsum_all(e);
        wbuf[lane*H+hh] = e / (Z + 1e-16f);
      }
      int j = 0;
      for (; j+2<S; j+=2){
        ushort4 n0, n1;
        n0 = *(const ushort4*)(hmat + (size_t)sbuf[j+2]*OUT + c0);
        n1 = n0;
        if (j+3 < S) n1 = *(const ushort4*)(hmat + (size_t)sbuf[j+3]*OUT + c0);
        float w0 = wbuf[j*H+head], w1 = wbuf[(j+1)*H+head];
        acc[0]=fmaf(w0,hu2f(a0.x),acc[0]); acc[1]=fmaf(w0,hu2f(a0.y),acc[1]);
        acc[2]=fmaf(w0,hu2f(a0.z),acc[2]); acc[3]=fmaf(w0,hu2f(a0.w),acc[3]);
        acc[0]=fmaf(w1,hu2f(a1.x),acc[0]); acc[1]=fmaf(w1,hu2f(a1.y),acc[1]);
        acc[2]=fmaf(w1,hu2f(a1.z),acc[2]); acc[3]=fmaf(w1,hu2f(a1.w),acc[3]);
        a0=n0; a1=n1;
      }
      {
        float w0 = wbuf[j*H+head];
        acc[0]=fmaf(w0,hu2f(a0.x),acc[0]); acc[1]=fmaf(w0,hu2f(a0.y),acc[1]);
        acc[2]=fmaf(w0,hu2f(a0.z),acc[2]); acc[3]=fmaf(w0,hu2f(a0.w),acc[3]);
        if (j+1 < S){
          float w1 = wbuf[(j+1)*H+head];
          acc[0]=fmaf(w1,hu2f(a1.x),acc[0]); acc[1]=fmaf(w1,hu2f(a1.y),acc[1]);
          acc[2]=fmaf(w1,hu2f(a1.z),acc[2]); acc[3]=fmaf(w1,hu2f(a1.w),acc[3]);
        }
      }
    }
  } else {
    float rm[H];
#pragma unroll
    for (int hh=0;hh<H;hh++) rm[hh] = -INFINITY;
    for (int s=lane; s<S; s+=64){
      int src = (s<deg)? csr_src[begin+s] : i;
      float ev = (s<deg)? csr_ea[begin+s] : lea;
#pragma unroll
      for (int hh=0;hh<H;hh++){
        float v = als[(size_t)src*H+hh] + aldi[hh] + ev*wei[hh];
        v = v>0.f? v : 0.2f*v;
        rm[hh] = fmaxf(rm[hh], v);
      }
    }
    float M[H], es[H];
#pragma unroll
    for (int hh=0;hh<H;hh++){ M[hh]=wmax_all(rm[hh]); es[hh]=0.f; }
    for (int s=lane; s<S; s+=64){
      int src = (s<deg)? csr_src[begin+s] : i;
      float ev = (s<deg)? csr_ea[begin+s] : lea;
#pragma unroll
      for (int hh=0;hh<H;hh++){
        float v = als[(size_t)src*H+hh] + aldi[hh] + ev*wei[hh];
        v = v>0.f? v : 0.2f*v;
        es[hh] += __expf(v - M[hh]);
      }
    }
    float invZ[H];
#pragma unroll
    for (int hh=0;hh<H;hh++) invZ[hh] = 1.f/(wsum_all(es[hh]) + 1e-16f);
    for (int cb=0; cb<S; cb+=64){
      int m = min(64, S-cb);
      int s = cb + lane;
      if (s < S){
        int src = (s<deg)? csr_src[begin+s] : i;
        float ev = (s<deg)? csr_ea[begin+s] : lea;
        sbuf[lane] = src;
#pragma unroll
        for (int hh=0;hh<H;hh++){
          float v = als[(size_t)src*H+hh] + aldi[hh] + ev*wei[hh];
          v = v>0.f? v : 0.2f*v;
          wbuf[lane*H+hh] = __expf(v - M[hh]) * invZ[hh];
        }
      }
      for (int j=0;j<m;j++){
        int sj = sbuf[j];
        float wj = wbuf[j*H+head];
        const unsigned short* row = hmat + (size_t)sj*OUT + c0;
        if constexpr (CPL==16){
          u16x8 r0 = *(const u16x8*)(row);
          u16x8 r1 = *(const u16x8*)(row+8);
#pragma unroll
          for (int c=0;c<8;c++){
            acc[c]   = fmaf(wj, hu2f(r0[c]), acc[c]);
            acc[8+c] = fmaf(wj, hu2f(r1[c]), acc[8+c]);
          }
        } else {
          ushort4 r = *(const ushort4*)(row);
          acc[0]=fmaf(wj,hu2f(r.x),acc[0]); acc[1]=fmaf(wj,hu2f(r.y),acc[1]);
          acc[2]=fmaf(wj,hu2f(r.z),acc[2]); acc[3]=fmaf(wj,hu2f(r.w),acc[3]);
        }
      }
    }
  }

  // ---- bias + LayerNorm + ReLU (wave-level) ----
  float vals[CPL];
  float ls=0.f;
#pragma unroll
  for (int c=0;c<CPL;c+=4){
    float4 b4 = *(const float4*)(bias + c0 + c);
    vals[c]=acc[c]+b4.x; vals[c+1]=acc[c+1]+b4.y; vals[c+2]=acc[c+2]+b4.z; vals[c+3]=acc[c+3]+b4.w;
    ls += vals[c]+vals[c+1]+vals[c+2]+vals[c+3];
  }
  float mu = wsum_all(ls) * (1.f/OUT);
  float lv=0.f;
#pragma unroll
  for (int c=0;c<CPL;c++){ float d=vals[c]-mu; lv += d*d; }
  float inv = rsqrtf(wsum_all(lv)*(1.f/OUT) + 1e-5f);

  if (outb){
    if constexpr (CPL==16){
#pragma unroll
      for (int c=0;c<CPL;c+=8){
        u16x8 o;
#pragma unroll
        for (int k=0;k<8;k++){
          float g = ln_g[c0+c+k], b = ln_b[c0+c+k];
          o[k] = f2hu(fmaxf((vals[c+k]-mu)*inv*g + b, 0.f));
        }
        *(u16x8*)(outb + (size_t)i*OUT + c0 + c) = o;
      }
    } else {
      ushort4 o;
      o.x = f2hu(fmaxf((vals[0]-mu)*inv*ln_g[c0+0] + ln_b[c0+0], 0.f));
      o.y = f2hu(fmaxf((vals[1]-mu)*inv*ln_g[c0+1] + ln_b[c0+1], 0.f));
      o.z = f2hu(fmaxf((vals[2]-mu)*inv*ln_g[c0+2] + ln_b[c0+2], 0.f));
      o.w = f2hu(fmaxf((vals[3]-mu)*inv*ln_g[c0+3] + ln_b[c0+3], 0.f));
      *(ushort4*)(outb + (size_t)i*OUT + c0) = o;
    }
  } else {
#pragma unroll
    for (int c=0;c<CPL;c+=4){
      float4 g4 = *(const float4*)(ln_g + c0 + c);
      float4 b4 = *(const float4*)(ln_b + c0 + c);
      float4 o;
      o.x = fmaxf((vals[c+0]-mu)*inv*g4.x + b4.x, 0.f);
      o.y = fmaxf((vals[c+1]-mu)*inv*g4.y + b4.y, 0.f);
      o.z = fmaxf((vals[c+2]-mu)*inv*g4.z + b4.z, 0.f);
      o.w = fmaxf((vals[c+3]-mu)*inv*g4.w + b4.w, 0.f);
      *(float4*)(outf + (size_t)i*OUT + c0 + c) = o;
    }
  }
}

// ---------------- mean pool + classifier ----------------
__global__ void colsum_kernel(const float* __restrict__ h2, float* __restrict__ gsum, int n){
  int c = threadIdx.x; // 256
  float acc=0;
  for (int i=blockIdx.x;i<n;i+=gridDim.x) acc += h2[(size_t)i*256 + c];
  atomicAdd(&gsum[c], acc);
}

__launch_bounds__(128)
__global__ void cls_kernel(const float* __restrict__ gsum,
                           const float* __restrict__ w1, const float* __restrict__ b1,
                           const float* __restrict__ w2, const float* __restrict__ b2,
                           float* __restrict__ outp){
  __shared__ float g[256];
  __shared__ float hid[128];
  int t = threadIdx.x;
  g[t]     = gsum[t]    *(1.f/N_NODES);
  g[t+128] = gsum[t+128]*(1.f/N_NODES);
  __syncthreads();
  float a = b1[t];
  for (int c=0;c<256;c++) a = fmaf(g[c], w1[c*128+t], a);
  hid[t] = fmaxf(a, 0.f);
  __syncthreads();
  if (t<2){
    float o = b2[t];
    for (int j=0;j<128;j++) o = fmaf(hid[j], w2[j*2+t], o);
    outp[t] = o;
  }
}

// ---------------- launch ----------------
extern "C" void kernel_launch(void* const* d_in, const int* in_sizes, int n_in,
                              void* d_out, int out_size, void* d_ws, size_t ws_size,
                              hipStream_t stream)
{
  const float* x      = (const float*)d_in[0];
  const int*   ei     = (const int*)  d_in[1];
  const float* ea     = (const float*)d_in[2];
  const float* ca_qw  = (const float*)d_in[3];
  const float* ca_kw  = (const float*)d_in[5];
  const float* ca_kb  = (const float*)d_in[6];
  const float* ca_vw  = (const float*)d_in[7];
  const float* ca_vb  = (const float*)d_in[8];
  const float* ca_ow  = (const float*)d_in[9];
  const float* ca_ob  = (const float*)d_in[10];
  const float* g0_w   = (const float*)d_in[11];
  const float* g0_ew  = (const float*)d_in[12];
  const float* g0_as  = (const float*)d_in[13];
  const float* g0_ad  = (const float*)d_in[14];
  const float* g0_ae  = (const float*)d_in[15];
  const float* g0_b   = (const float*)d_in[16];
  const float* ln0_g  = (const float*)d_in[17];
  const float* ln0_b  = (const float*)d_in[18];
  const float* g1_w   = (const float*)d_in[19];
  const float* g1_ew  = (const float*)d_in[20];
  const float* g1_as  = (const float*)d_in[21];
  const float* g1_ad  = (const float*)d_in[22];
  const float* g1_ae  = (const float*)d_in[23];
  const float* g1_b   = (const float*)d_in[24];
  const float* ln1_g  = (const float*)d_in[25];
  const float* ln1_b  = (const float*)d_in[26];
  const float* g2_w   = (const float*)d_in[27];
  const float* g2_ew  = (const float*)d_in[28];
  const float* g2_as  = (const float*)d_in[29];
  const float* g2_ad  = (const float*)d_in[30];
  const float* g2_ae  = (const float*)d_in[31];
  const float* g2_b   = (const float*)d_in[32];
  const float* ln2_g  = (const float*)d_in[33];
  const float* ln2_b  = (const float*)d_in[34];
  const float* cls_w1 = (const float*)d_in[35];
  const float* cls_b1 = (const float*)d_in[36];
  const float* cls_w2 = (const float*)d_in[37];
  const float* cls_b2 = (const float*)d_in[38];
  float* outp = (float*)d_out;

  const int N = N_NODES, E = N_EDGES;

  char* base = (char*)d_ws;
  size_t o = 0;
  auto alloc = [&](size_t bytes)->void*{
    void* p = base + o;
    o += (bytes + 255) & ~(size_t)255;
    return p;
  };
  unsigned short* hF   = (unsigned short*)alloc((size_t)N*1024*2); // GEMM output h (f16)
  unsigned short* Af   = (unsigned short*)alloc((size_t)N*1280*2); // f16 activations (x, then agg out)
  float*          h2   = (float*)         alloc((size_t)N*256*4);  // layer-2 agg out (f32)
  unsigned short* Wt   = (unsigned short*)alloc((size_t)1280*1024*2);
  float* alsp      = (float*)alloc((size_t)8*N*4);    // per-tile partials
  float* aldp      = (float*)alloc((size_t)8*N*4);
  float* als       = (float*)alloc((size_t)2*N*4*4);  // als | ald contiguous
  float* ald       = als + (size_t)N*4;
  float* scores    = (float*)alloc((size_t)N*4);
  float* wts       = (float*)alloc((size_t)N*4);
  int*   cnt       = (int*)  alloc((size_t)N*4);
  float* easum     = (float*)alloc((size_t)N*4);
  int*   off       = (int*)  alloc((size_t)(N+1)*4);
  int*   fill      = (int*)  alloc((size_t)N*4);
  int*   csr_src   = (int*)  alloc((size_t)E*4);
  float* csr_ea    = (float*)alloc((size_t)E*4);
  float* loop_attr = (float*)alloc((size_t)N*4);
  float* Kv        = (float*)alloc(256*4);
  float* Vv        = (float*)alloc(256*4);
  float* qK        = (float*)alloc(1280*4);
  float* Vo        = (float*)alloc(1280*4);
  float* obW       = (float*)alloc(1024*4);
  float* VoW       = (float*)alloc(1024*4);
  float* web       = (float*)alloc(16*4);
  float* gsum      = (float*)alloc(256*4);

  hipMemsetAsync(cnt,   0, (size_t)N*4, stream);
  hipMemsetAsync(easum, 0, (size_t)N*4, stream);
  hipMemsetAsync(fill,  0, (size_t)N*4, stream);
  hipMemsetAsync(gsum,  0, 256*4,       stream);
  hipMemsetAsync(obW,   0, 1024*4,      stream);
  hipMemsetAsync(VoW,   0, 1024*4,      stream);

  // ---- edge preprocessing (CSR by dst) ----
  int eblocks = (E + 255)/256;
  edge_count_kernel<<<eblocks,256,0,stream>>>(ei, ea, cnt, easum, E);
  scan_kernel<<<1,1024,0,stream>>>(cnt, easum, off, loop_attr, N);
  edge_fill_kernel<<<eblocks,256,0,stream>>>(ei, ea, off, fill, csr_src, csr_ea, E);

  // ---- cross-attention, rank-1 collapsed ----
  kv_kernel<<<1,256,0,stream>>>(x, ca_kw, ca_kb, ca_vw, ca_vb, Kv, Vv);
  qkvo_kernel<<<25,256,0,stream>>>(ca_qw, ca_ow, Kv, Vv, qK, Vo);
  xh_scores_kernel<<<(N+3)/4,256,0,stream>>>(x, qK, Af, scores, N);
  obw_kernel<<<dim3(4,10),256,0,stream>>>(ca_ob, Vo, g0_w, obW, VoW);
  softmax_nodes<<<1,1024,0,stream>>>(scores, wts, N);

  const int mTiles  = (N + 127)/128;      // 157
  const int mGroups = (mTiles + 7)/8;     // 20
  const int NB4 = (N + 3)/4;              // wave-per-node blocks

  // ---- layer 0 ----
  wt_f16_kernel<<<dim3(1280/32, 1024/32),256,0,stream>>>(g0_w, 1280, 1024, Wt);
  gemm_f16<<<dim3(8, mGroups*8),256,0,stream>>>(Af, Wt, hF, N, 1024, 1280, obW, VoW, wts,
                                                g0_as, g0_ad, alsp, aldp);
  als_combine<<<(N*4+255)/256,256,0,stream>>>(alsp, aldp, als, ald, N, 4, g0_ew, g0_ae, web);
  gat_agg_ln_wave<4><<<NB4,256,0,stream>>>(hF, als, ald, off, csr_src, csr_ea, loop_attr,
                                           web, g0_b, ln0_g, ln0_b, nullptr, Af, N);

  // ---- layer 1 ----
  wt_f16_kernel<<<dim3(1024/32, 1024/32),256,0,stream>>>(g1_w, 1024, 1024, Wt);
  gemm_f16<<<dim3(8, mGroups*8),256,0,stream>>>(Af, Wt, hF, N, 1024, 1024, nullptr, nullptr, nullptr,
                                                g1_as, g1_ad, alsp, aldp);
  als_combine<<<(N*4+255)/256,256,0,stream>>>(alsp, aldp, als, ald, N, 4, g1_ew, g1_ae, web);
  gat_agg_ln_wave<4><<<NB4,256,0,stream>>>(hF, als, ald, off, csr_src, csr_ea, loop_attr,
                                           web, g1_b, ln1_g, ln1_b, nullptr, Af, N);

  // ---- layer 2 (1 head, 256 out) ----
  wt_f16_kernel<<<dim3(1024/32, 256/32),256,0,stream>>>(g2_w, 1024, 256, Wt);
  gemm_f16<<<dim3(8, mGroups*2),256,0,stream>>>(Af, Wt, hF, N, 256, 1024, nullptr, nullptr, nullptr,
                                                g2_as, g2_ad, alsp, aldp);
  als_combine<<<(N+255)/256,256,0,stream>>>(alsp, aldp, als, ald, N, 1, g2_ew, g2_ae, web);
  gat_agg_ln_wave<1><<<NB4,256,0,stream>>>(hF, als, ald, off, csr_src, csr_ea, loop_attr,
                                           web, g2_b, ln2_g, ln2_b, h2, nullptr, N);

  // ---- mean pool + classifier ----
  colsum_kernel<<<256,256,0,stream>>>(h2, gsum, N);
  cls_kernel<<<1,128,0,stream>>>(gsum, cls_w1, cls_b1, cls_w2, cls_b2, outp);

  (void)in_sizes; (void)n_in; (void)out_size; (void)ws_size;
}

// Round 6
// 798.783 us; speedup vs baseline: 1.1282x; 1.0024x over previous
//
#include <hip/hip_runtime.h>
#include <hip/hip_bf16.h>
#include <math.h>

#define N_NODES 20000
#define N_EDGES 200000
#define XROW    1480   // EMB + MD

typedef __attribute__((ext_vector_type(8))) _Float16 f16x8;
typedef __attribute__((ext_vector_type(8))) unsigned short u16x8;
typedef __attribute__((ext_vector_type(4))) float f32x4v;

// ---------------- reduction helpers ----------------
__device__ __forceinline__ float wsum(float v){
#pragma unroll
  for (int o=32;o>0;o>>=1) v += __shfl_down(v,o);
  return v;
}
__device__ __forceinline__ float wmax(float v){
#pragma unroll
  for (int o=32;o>0;o>>=1) v = fmaxf(v,__shfl_down(v,o));
  return v;
}
// butterfly: result in ALL lanes
__device__ __forceinline__ float wsum_all(float v){
#pragma unroll
  for (int o=32;o>0;o>>=1) v += __shfl_xor(v,o);
  return v;
}
__device__ __forceinline__ float wmax_all(float v){
#pragma unroll
  for (int o=32;o>0;o>>=1) v = fmaxf(v,__shfl_xor(v,o));
  return v;
}

__device__ __forceinline__ unsigned short f2hu(float f){
  _Float16 h = (_Float16)f;
  return __builtin_bit_cast(unsigned short, h);
}
__device__ __forceinline__ float hu2f(unsigned short u){
  return (float)__builtin_bit_cast(_Float16, u);
}

__device__ __forceinline__ void async_copy16(void* lds, const void* g){
  __builtin_amdgcn_global_load_lds((const __attribute__((address_space(1))) void*)g,
                                   (__attribute__((address_space(3))) void*)lds, 16, 0, 0);
}

// ---------------- edge preprocessing (once, reused 3 layers) ----------------
__global__ void edge_count_kernel(const int* __restrict__ ei, const float* __restrict__ ea,
                                  int* __restrict__ cnt, float* __restrict__ easum, int E){
  int e = blockIdx.x*256 + threadIdx.x;
  if (e >= E) return;
  int dst = ei[E + e];
  atomicAdd(&cnt[dst], 1);
  atomicAdd(&easum[dst], ea[e]);
}

// thread-serial chunk of 20 + single 1024 Kogge-Stone scan
__launch_bounds__(1024)
__global__ void scan_kernel(const int* __restrict__ cnt, const float* __restrict__ easum,
                            int* __restrict__ off, float* __restrict__ loop_attr, int n){
  __shared__ int buf[1024];
  const int PER = (N_NODES + 1023)/1024;   // 20
  int t = threadIdx.x;
  int base = t*PER;
  int local[PER];
  int s = 0;
#pragma unroll
  for (int k=0;k<PER;k++){
    int i = base + k;
    int v = (i<n)? cnt[i] : 0;
    local[k] = v;
    s += v;
  }
  buf[t] = s;
  __syncthreads();
  for (int d2=1; d2<1024; d2<<=1){
    int tv = (t>=d2)? buf[t-d2] : 0;
    __syncthreads();
    buf[t] += tv;
    __syncthreads();
  }
  int run = buf[t] - s;   // exclusive prefix of this thread's chunk
#pragma unroll
  for (int k=0;k<PER;k++){
    int i = base + k;
    if (i < n){
      off[i] = run;
      int v = local[k];
      loop_attr[i] = (v>0) ? easum[i]/(float)v : 0.f;  // fill='mean'
      run += v;
    }
  }
  if (t == 1023) off[n] = buf[1023];
}

__global__ void edge_fill_kernel(const int* __restrict__ ei, const float* __restrict__ ea,
                                 const int* __restrict__ off, int* __restrict__ fill,
                                 int* __restrict__ csr_src, float* __restrict__ csr_ea, int E){
  int e = blockIdx.x*256 + threadIdx.x;
  if (e >= E) return;
  int dst = ei[E + e];
  int pos = off[dst] + atomicAdd(&fill[dst], 1);
  csr_src[pos] = ei[e];
  csr_ea[pos]  = ea[e];
}

// ---------------- conversions ----------------
// transpose: W[K,N] f32 -> Wt[N,K] f16
__global__ void wt_f16_kernel(const float* __restrict__ W, int K, int N,
                              unsigned short* __restrict__ Wt){
  __shared__ float tile[32][33];
  int k0 = blockIdx.x*32, n0 = blockIdx.y*32;
  int tx = threadIdx.x & 31, ty = threadIdx.x >> 5; // 32 x 8
  for (int r=ty; r<32; r+=8) tile[r][tx] = W[(size_t)(k0+r)*N + n0+tx];
  __syncthreads();
  for (int r=ty; r<32; r+=8){
    float w = tile[tx][r];               // = W[k0+tx][n0+r]
    Wt[(size_t)(n0+r)*K + k0+tx] = f2hu(w);
  }
}

// ---------------- cross-attention (rank-1 collapsed) ----------------
__global__ void kv_kernel(const float* __restrict__ x,
                          const float* __restrict__ kw, const float* __restrict__ kb,
                          const float* __restrict__ vw, const float* __restrict__ vb,
                          float* __restrict__ Kv, float* __restrict__ Vv){
  int j = threadIdx.x; // 256
  float ka = kb[j], va = vb[j];
  for (int k=0;k<200;k++){
    float m = x[1280+k];
    ka = fmaf(m, kw[k*256+j], ka);
    va = fmaf(m, vw[k*256+j], va);
  }
  Kv[j]=ka; Vv[j]=va;
}

// qK via wave-per-row (coalesced float4 lane loads + shuffle reduce, 20 blocks);
// Vo via thread-per-column (coalesced, 5 blocks). 25 blocks total.
__global__ void qkvo_kernel(const float* __restrict__ qw, const float* __restrict__ ow,
                            const float* __restrict__ Kv, const float* __restrict__ Vv,
                            float* __restrict__ qK, float* __restrict__ Vo){
  int b = blockIdx.x;
  if (b < 20){
    int wv = threadIdx.x>>6, lane = threadIdx.x&63;
    float4 k4 = ((const float4*)Kv)[lane];
    int w0 = b*4 + wv;                 // 80 waves
    for (int r = w0; r < 1280; r += 80){
      float4 q = *(const float4*)(qw + (size_t)r*256 + lane*4);
      float v = q.x*k4.x + q.y*k4.y + q.z*k4.z + q.w*k4.w;
      v = wsum(v);
      if (lane==0) qK[r] = v;
    }
  } else {
    int j = (b-20)*256 + threadIdx.x;  // < 1280
    float a=0;
    for (int i=0;i<256;i++) a = fmaf(Vv[i], ow[(size_t)i*1280+j], a);
    Vo[j]=a;
  }
}

// i-split partials (grid 4 x 10), atomicAdd combine. (was a hidden 4-block hog)
__global__ void obw_kernel(const float* __restrict__ ob, const float* __restrict__ Vo,
                           const float* __restrict__ W, float* __restrict__ obW, float* __restrict__ VoW){
  int j = blockIdx.x*256 + threadIdx.x; // < 1024
  int i0 = blockIdx.y*128;
  float a=0,b=0;
  for (int i=i0;i<i0+128;i++){
    float w = W[(size_t)i*1024+j];
    a = fmaf(ob[i], w, a);
    b = fmaf(Vo[i], w, b);
  }
  atomicAdd(&obW[j], a);
  atomicAdd(&VoW[j], b);
}

// FUSED x f32 -> f16 conversion + scores dot (reads x once, writes Af + scores).
__launch_bounds__(256)
__global__ void xh_scores_kernel(const float* __restrict__ x, const float* __restrict__ qK,
                                 unsigned short* __restrict__ xh, float* __restrict__ scores, int n){
  __shared__ float qs[1280];
  int t = threadIdx.x;
  for (int i=t;i<1280;i+=256) qs[i]=qK[i];
  __syncthreads();
  int wid = t>>6, lane = t&63;
  int node = blockIdx.x*4 + wid;
  if (node >= n) return;
  const float* xr = x + (size_t)node*XROW;
  unsigned short* orow = xh + (size_t)node*1280;
  float acc = 0.f;
#pragma unroll
  for (int it=0; it<5; it++){
    int c4 = it*64 + lane;           // < 320
    float4 v = *(const float4*)(xr + c4*4);
    ushort4 o;
    o.x = f2hu(v.x); o.y = f2hu(v.y); o.z = f2hu(v.z); o.w = f2hu(v.w);
    *(ushort4*)(orow + c4*4) = o;
    acc = fmaf(v.x, qs[c4*4+0], acc);
    acc = fmaf(v.y, qs[c4*4+1], acc);
    acc = fmaf(v.z, qs[c4*4+2], acc);
    acc = fmaf(v.w, qs[c4*4+3], acc);
  }
  acc = wsum(acc);
  if (lane==0) scores[node] = acc;
}

__launch_bounds__(1024)
__global__ void softmax_nodes(const float* __restrict__ scores, float* __restrict__ wts, int n){
  __shared__ float red[16];
  int t = threadIdx.x, lane=t&63, wid=t>>6;
  float m = -INFINITY;
  for (int i=t;i<n;i+=1024) m = fmaxf(m, scores[i]);
  m = wmax(m);
  if (lane==0) red[wid]=m;
  __syncthreads();
  if (t==0){ float r=red[0]; for (int k=1;k<16;k++) r=fmaxf(r,red[k]); red[0]=r; }
  __syncthreads();
  float M = red[0];
  __syncthreads();
  float z=0;
  for (int i=t;i<n;i+=1024) z += __expf((scores[i]-M)*(1.f/16.f));
  z = wsum(z);
  if (lane==0) red[wid]=z;
  __syncthreads();
  if (t==0){ float r=0; for (int k=0;k<16;k++) r+=red[k]; red[0]=r; }
  __syncthreads();
  float invZ = 1.f/red[0];
  for (int i=t;i<n;i+=1024) wts[i] = __expf((scores[i]-M)*(1.f/16.f))*invZ;
}

// ---------------- f16 MFMA GEMM (TN): C[M,N] = A[M,K] @ B[N,K]^T ----------------
// v3: BK=32, LDS 32 KB (2 dbuf x [A 8KB | B 8KB]) -> ~5 blocks/CU (was 2 at
// BK=64/64KB). Counted-vmcnt dbuf schedule kept: issue next tile's 4 loads,
// vmcnt(4), barrier, 8 ds_read + 16 MFMA, barrier. Latency cover now comes
// from co-resident blocks (m114 implicit overlap — the mechanism behind the
// m97 874 TF reference at 3 blocks/CU).
// SUPERROW swizzle (BK=32 rows are 64B, too narrow for the old row-XOR):
// pair rows into 128B superrows of 8 x 16B slots;
//   phys_slot = ((r&1)*4 + c) ^ ((r>>1)&7)
// A wave's 64 lanes (4 c-quarters x 16 rows) hit 64 DISTINCT slots tiling a
// contiguous 1KB slab -> conflict-free. Staging keeps the wave-linear dest;
// the global source is pre-swizzled with the same involution.
__launch_bounds__(256)
__global__ void gemm_f16(const unsigned short* __restrict__ A,
                         const unsigned short* __restrict__ B,
                         unsigned short* __restrict__ C, int M, int N, int K,
                         const float* __restrict__ addCol,   // obW or null
                         const float* __restrict__ vCol,     // VoW
                         const float* __restrict__ wRow,     // wts
                         const float* __restrict__ a_src,    // [N] flat
                         const float* __restrict__ a_dst,
                         float* __restrict__ alsp,           // [ntc][M] partials
                         float* __restrict__ aldp)
{
  __shared__ short lds[2*2*128*32];       // 32 KB: [buf][A 4096 | B 4096] shorts

  const int ntc = N >> 7;                 // N-tiles (pow2: 8 or 2)
  const int sh  = __popc(ntc - 1);
  const int g   = blockIdx.y >> sh;
  const int nt  = blockIdx.y & (ntc - 1);
  const int band = blockIdx.x + (g << 3); // bx + 8*g
  if (band * 128 >= M) return;

  const int t = threadIdx.x;
  const int w = t>>6, l = t&63;
  const int bm = band*128, bn = nt*128;
  const int wr = (w>>1)*64, wc = (w&1)*64;
  const int half = w & 1;                 // which 64-col half of the tile

  f32x4v acc[4][4];
#pragma unroll
  for (int i=0;i<4;i++)
#pragma unroll
    for (int j=0;j<4;j++) acc[i][j] = (f32x4v){0.f,0.f,0.f,0.f};

  // stage pointers: chunk p = (w*2+q)*64 + l in [0,512) per region.
  // decode phys chunk -> logical (row, k-chunk) via the superrow involution.
  const unsigned short* Ap[2]; const unsigned short* Bp[2];
  int ldsOff[2];
#pragma unroll
  for (int q=0;q<2;q++){
    int p    = (w*2+q)*64 + l;
    int sr   = p>>3, slot = p&7;
    int sl   = slot ^ (sr&7);
    int r    = sr*2 + (sl>>2);
    int kc   = (sl&3)*8;            // element offset within the 32-k tile
    int rowA = bm + r; if (rowA > M-1) rowA = M-1;
    Ap[q] = A + (size_t)rowA*K + kc;
    Bp[q] = B + (size_t)(bn+r)*K + kc;
    ldsOff[q] = (w*2+q)*512;        // shorts (wave-uniform base; lane spreads x16B)
  }

  const int nsteps = K >> 5;              // 40 / 32 / 32

  // prologue: stage tile 0 -> buffer 0 (4 loads/wave in flight)
#pragma unroll
  for (int q=0;q<2;q++) async_copy16(lds + ldsOff[q],        Ap[q]);
#pragma unroll
  for (int q=0;q<2;q++) async_copy16(lds + 4096 + ldsOff[q], Bp[q]);

  const int q4 = l>>4, m16 = l&15;

  for (int kt=0; kt<nsteps; ++kt){
    short* curb = lds + (kt&1)*8192;

    if (kt+1 < nsteps){
      // issue next tile's stage -> other buffer; stays in flight across barriers
      short* nxt = lds + ((kt+1)&1)*8192;
      const int k0n = (kt+1)*32;
#pragma unroll
      for (int q=0;q<2;q++) async_copy16(nxt + ldsOff[q],        Ap[q] + k0n);
#pragma unroll
      for (int q=0;q<2;q++) async_copy16(nxt + 4096 + ldsOff[q], Bp[q] + k0n);
      // wait only for CURRENT tile's 4 loads (4 newest = next tile remain out)
      asm volatile("s_waitcnt vmcnt(4)" ::: "memory");
    } else {
      asm volatile("s_waitcnt vmcnt(0)" ::: "memory");
    }
    __builtin_amdgcn_sched_barrier(0);
    __builtin_amdgcn_s_barrier();          // raw: no vmcnt(0) drain
    __builtin_amdgcn_sched_barrier(0);     // keep ds_reads below the barrier

    __builtin_amdgcn_s_setprio(1);
    {
      f16x8 af[4], bf[4];
#pragma unroll
      for (int i=0;i<4;i++){
        int ra = wr + i*16 + m16;
        af[i] = *(const f16x8*)&curb[(ra>>1)*64 + ((((((ra&1)<<2)+q4)) ^ ((ra>>1)&7))<<3)];
        int rb = wc + i*16 + m16;
        bf[i] = *(const f16x8*)&curb[4096 + (rb>>1)*64 + ((((((rb&1)<<2)+q4)) ^ ((rb>>1)&7))<<3)];
      }
#pragma unroll
      for (int i=0;i<4;i++)
#pragma unroll
        for (int j=0;j<4;j++)
          acc[i][j] = __builtin_amdgcn_mfma_f32_16x16x32_f16(af[i], bf[j], acc[i][j], 0,0,0);
    }
    __builtin_amdgcn_s_setprio(0);
    __builtin_amdgcn_sched_barrier(0);     // all ds_reads of curb retired
    __builtin_amdgcn_s_barrier();          // now next iter may overwrite curb
    __builtin_amdgcn_sched_barrier(0);
  }

  // epilogue: C/D layout col = l&15, row = (l>>4)*4 + r ; f32 math then f16 store.
  float* sred = (float*)lds;          // [2][128]
  float* dred = sred + 256;           // [2][128]
  float asv[4], adv[4];
#pragma unroll
  for (int j=0;j<4;j++){
    int n = bn + wc + j*16 + m16;
    asv[j] = a_src[n];
    adv[j] = a_dst[n];
  }
#pragma unroll
  for (int i=0;i<4;i++){
#pragma unroll
    for (int r=0;r<4;r++){
      int rloc = wr + i*16 + q4*4 + r;
      int m = bm + rloc;
      float wrow = addCol ? wRow[m < M ? m : M-1] : 0.f;
      float vj[4];
#pragma unroll
      for (int j=0;j<4;j++){
        int n = bn + wc + j*16 + m16;
        float v = acc[i][j][r];
        if (addCol) v += addCol[n] + wrow*vCol[n];
        vj[j] = v;
      }
      if (m < M){
        unsigned short* crow = C + (size_t)m*N;
#pragma unroll
        for (int j=0;j<4;j++) crow[bn + wc + j*16 + m16] = f2hu(vj[j]);
      }
      float s = vj[0]*asv[0] + vj[1]*asv[1] + vj[2]*asv[2] + vj[3]*asv[3];
      float d = vj[0]*adv[0] + vj[1]*adv[1] + vj[2]*adv[2] + vj[3]*adv[3];
#pragma unroll
      for (int o=1;o<16;o<<=1){ s += __shfl_xor(s,o); d += __shfl_xor(d,o); }
      if (m16 == 0){
        sred[half*128 + rloc] = s;
        dred[half*128 + rloc] = d;
      }
    }
  }
  __syncthreads();
  if (t < 128){
    int m = bm + t;
    if (m < M){
      alsp[(size_t)nt*M + m] = sred[t] + sred[128+t];
      aldp[(size_t)nt*M + m] = dred[t] + dred[128+t];
    }
  }
}

// combine per-tile partials -> als/ald [m*H+hh]; each head spans 2 column tiles.
// Block 0 additionally computes we[h].
__global__ void als_combine(const float* __restrict__ alsp, const float* __restrict__ aldp,
                            float* __restrict__ als, float* __restrict__ ald, int M, int H,
                            const float* __restrict__ We, const float* __restrict__ a_edge,
                            float* __restrict__ we){
  if (blockIdx.x == 0){
    int wid = threadIdx.x>>6, lane = threadIdx.x&63;
    if (wid < H){
      const float4* w4 = (const float4*)(We + wid*256);
      const float4* a4 = (const float4*)(a_edge + wid*256);
      float4 a = w4[lane], b = a4[lane];
      float v = a.x*b.x + a.y*b.y + a.z*b.z + a.w*b.w;
      v = wsum(v);
      if (lane==0) we[wid]=v;
    }
  }
  int idx = blockIdx.x*256 + threadIdx.x;
  if (idx >= M*H) return;
  int m = idx / H, hh = idx - m*H;
  als[idx] = alsp[(size_t)(2*hh)*M + m] + alsp[(size_t)(2*hh+1)*M + m];
  ald[idx] = aldp[(size_t)(2*hh)*M + m] + aldp[(size_t)(2*hh+1)*M + m];
}

// ---------------- fused alpha-softmax + aggregate + bias + LN + ReLU ----------------
// ONE WAVE PER NODE (4 waves/block). Gather j-loop pairwise-unrolled with
// depth-1 prefetch.
template<int H>
__launch_bounds__(256)
__global__ void gat_agg_ln_wave(const unsigned short* __restrict__ hmat,
                           const float* __restrict__ als, const float* __restrict__ ald,
                           const int* __restrict__ off, const int* __restrict__ csr_src,
                           const float* __restrict__ csr_ea, const float* __restrict__ loop_attr,
                           const float* __restrict__ we,
                           const float* __restrict__ bias,
                           const float* __restrict__ ln_g, const float* __restrict__ ln_b,
                           float* __restrict__ outf, unsigned short* __restrict__ outb, int n)
{
  constexpr int OUT = 256*H;      // 1024 or 256
  constexpr int CPL = OUT/64;     // channels per lane: 16 or 4
  const int wv = threadIdx.x>>6, lane = threadIdx.x&63;
  const int i = blockIdx.x*4 + wv;
  __shared__ float wbuf_s[4][64*H];
  __shared__ int   sbuf_s[4][64];
  if (i >= n) return;
  float* wbuf = wbuf_s[wv];
  int*   sbuf = sbuf_s[wv];

  const int begin = off[i];
  const int deg   = off[i+1]-begin;
  const int S     = deg + 1;           // + self-loop

  float aldi[H], wei[H];
#pragma unroll
  for (int hh=0;hh<H;hh++){ aldi[hh]=ald[(size_t)i*H+hh]; wei[hh]=we[hh]; }
  const float lea = loop_attr[i];

  const int head = (lane*CPL) >> 8;
  const int c0   = lane*CPL;
  float acc[CPL];
#pragma unroll
  for (int c=0;c<CPL;c++) acc[c]=0.f;

  if (S <= 64){
    int src = i; float ev = lea;
    if (lane < deg){ src = csr_src[begin+lane]; ev = csr_ea[begin+lane]; }
    const bool act = lane < S;
    sbuf[lane] = src;

    if constexpr (CPL==16){
      u16x8 a0r0,a0r1,a1r0,a1r1;
      {
        const unsigned short* r0p = hmat + (size_t)sbuf[0]*OUT + c0;
        a0r0 = *(const u16x8*)r0p; a0r1 = *(const u16x8*)(r0p+8);
        a1r0 = a0r0; a1r1 = a0r1;
        if (S > 1){
          const unsigned short* r1p = hmat + (size_t)sbuf[1]*OUT + c0;
          a1r0 = *(const u16x8*)r1p; a1r1 = *(const u16x8*)(r1p+8);
        }
      }
      float a[H];
#pragma unroll
      for (int hh=0;hh<H;hh++){
        float v = als[(size_t)src*H+hh] + aldi[hh] + ev*wei[hh];
        a[hh] = v>0.f ? v : 0.2f*v;
      }
#pragma unroll
      for (int hh=0;hh<H;hh++){
        float M = wmax_all(act ? a[hh] : -INFINITY);
        float e = act ? __expf(a[hh]-M) : 0.f;
        float Z = wsum_all(e);
        wbuf[lane*H+hh] = e / (Z + 1e-16f);
      }
      int j = 0;
      for (; j+2<S; j+=2){
        u16x8 n0r0,n0r1,n1r0,n1r1;
        {
          const unsigned short* rp = hmat + (size_t)sbuf[j+2]*OUT + c0;
          n0r0 = *(const u16x8*)rp; n0r1 = *(const u16x8*)(rp+8);
          n1r0 = n0r0; n1r1 = n0r1;
          if (j+3 < S){
            const unsigned short* rq = hmat + (size_t)sbuf[j+3]*OUT + c0;
            n1r0 = *(const u16x8*)rq; n1r1 = *(const u16x8*)(rq+8);
          }
        }
        float w0 = wbuf[j*H+head], w1 = wbuf[(j+1)*H+head];
#pragma unroll
        for (int c=0;c<8;c++){
          acc[c]   = fmaf(w0, hu2f(a0r0[c]), acc[c]);
          acc[8+c] = fmaf(w0, hu2f(a0r1[c]), acc[8+c]);
        }
#pragma unroll
        for (int c=0;c<8;c++){
          acc[c]   = fmaf(w1, hu2f(a1r0[c]), acc[c]);
          acc[8+c] = fmaf(w1, hu2f(a1r1[c]), acc[8+c]);
        }
        a0r0=n0r0; a0r1=n0r1; a1r0=n1r0; a1r1=n1r1;
      }
      {
        float w0 = wbuf[j*H+head];
#pragma unroll
        for (int c=0;c<8;c++){
          acc[c]   = fmaf(w0, hu2f(a0r0[c]), acc[c]);
          acc[8+c] = fmaf(w0, hu2f(a0r1[c]), acc[8+c]);
        }
        if (j+1 < S){
          float w1 = wbuf[(j+1)*H+head];
#pragma unroll
          for (int c=0;c<8;c++){
            acc[c]   = fmaf(w1, hu2f(a1r0[c]), acc[c]);
            acc[8+c] = fmaf(w1, hu2f(a1r1[c]), acc[8+c]);
          }
        }
      }
    } else {
      ushort4 a0, a1;
      {
        a0 = *(const ushort4*)(hmat + (size_t)sbuf[0]*OUT + c0);
        a1 = a0;
        if (S > 1) a1 = *(const ushort4*)(hmat + (size_t)sbuf[1]*OUT + c0);
      }
      float a[H];
#pragma unroll
      for (int hh=0;hh<H;hh++){
        float v = als[(size_t)src*H+hh] + aldi[hh] + ev*wei[hh];
        a[hh] = v>0.f ? v : 0.2f*v;
      }
#pragma unroll
      for (int hh=0;hh<H;hh++){
        float M = wmax_all(act ? a[hh] : -INFINITY);
        float e = act ? __expf(a[hh]-M) : 0.f;
        float Z = wsum_all(e);
        wbuf[lane*H+hh] = e / (Z + 1e-16f);
      }
      int j = 0;
      for (; j+2<S; j+=2){
        ushort4 n0, n1;
        n0 = *(const ushort4*)(hmat + (size_t)sbuf[j+2]*OUT + c0);
        n1 = n0;
        if (j+3 < S) n1 = *(const ushort4*)(hmat + (size_t)sbuf[j+3]*OUT + c0);
        float w0 = wbuf[j*H+head], w1 = wbuf[(j+1)*H+head];
        acc[0]=fmaf(w0,hu2f(a0.x),acc[0]); acc[1]=fmaf(w0,hu2f(a0.y),acc[1]);
        acc[2]=fmaf(w0,hu2f(a0.z),acc[2]); acc[3]=fmaf(w0,hu2f(a0.w),acc[3]);
        acc[0]=fmaf(w1,hu2f(a1.x),acc[0]); acc[1]=fmaf(w1,hu2f(a1.y),acc[1]);
        acc[2]=fmaf(w1,hu2f(a1.z),acc[2]); acc[3]=fmaf(w1,hu2f(a1.w),acc[3]);
        a0=n0; a1=n1;
      }
      {
        float w0 = wbuf[j*H+head];
        acc[0]=fmaf(w0,hu2f(a0.x),acc[0]); acc[1]=fmaf(w0,hu2f(a0.y),acc[1]);
        acc[2]=fmaf(w0,hu2f(a0.z),acc[2]); acc[3]=fmaf(w0,hu2f(a0.w),acc[3]);
        if (j+1 < S){
          float w1 = wbuf[(j+1)*H+head];
          acc[0]=fmaf(w1,hu2f(a1.x),acc[0]); acc[1]=fmaf(w1,hu2f(a1.y),acc[1]);
          acc[2]=fmaf(w1,hu2f(a1.z),acc[2]); acc[3]=fmaf(w1,hu2f(a1.w),acc[3]);
        }
      }
    }
  } else {
    float rm[H];
#pragma unroll
    for (int hh=0;hh<H;hh++) rm[hh] = -INFINITY;
    for (int s=lane; s<S; s+=64){
      int src = (s<deg)? csr_src[begin+s] : i;
      float ev = (s<deg)? csr_ea[begin+s] : lea;
#pragma unroll
      for (int hh=0;hh<H;hh++){
        float v = als[(size_t)src*H+hh] + aldi[hh] + ev*wei[hh];
        v = v>0.f? v : 0.2f*v;
        rm[hh] = fmaxf(rm[hh], v);
      }
    }
    float M[H], es[H];
#pragma unroll
    for (int hh=0;hh<H;hh++){ M[hh]=wmax_all(rm[hh]); es[hh]=0.f; }
    for (int s=lane; s<S; s+=64){
      int src = (s<deg)? csr_src[begin+s] : i;
      float ev = (s<deg)? csr_ea[begin+s] : lea;
#pragma unroll
      for (int hh=0;hh<H;hh++){
        float v = als[(size_t)src*H+hh] + aldi[hh] + ev*wei[hh];
        v = v>0.f? v : 0.2f*v;
        es[hh] += __expf(v - M[hh]);
      }
    }
    float invZ[H];
#pragma unroll
    for (int hh=0;hh<H;hh++) invZ[hh] = 1.f/(wsum_all(es[hh]) + 1e-16f);
    for (int cb=0; cb<S; cb+=64){
      int m = min(64, S-cb);
      int s = cb + lane;
      if (s < S){
        int src = (s<deg)? csr_src[begin+s] : i;
        float ev = (s<deg)? csr_ea[begin+s] : lea;
        sbuf[lane] = src;
#pragma unroll
        for (int hh=0;hh<H;hh++){
          float v = als[(size_t)src*H+hh] + aldi[hh] + ev*wei[hh];
          v = v>0.f? v : 0.2f*v;
          wbuf[lane*H+hh] = __expf(v - M[hh]) * invZ[hh];
        }
      }
      for (int j=0;j<m;j++){
        int sj = sbuf[j];
        float wj = wbuf[j*H+head];
        const unsigned short* row = hmat + (size_t)sj*OUT + c0;
        if constexpr (CPL==16){
          u16x8 r0 = *(const u16x8*)(row);
          u16x8 r1 = *(const u16x8*)(row+8);
#pragma unroll
          for (int c=0;c<8;c++){
            acc[c]   = fmaf(wj, hu2f(r0[c]), acc[c]);
            acc[8+c] = fmaf(wj, hu2f(r1[c]), acc[8+c]);
          }
        } else {
          ushort4 r = *(const ushort4*)(row);
          acc[0]=fmaf(wj,hu2f(r.x),acc[0]); acc[1]=fmaf(wj,hu2f(r.y),acc[1]);
          acc[2]=fmaf(wj,hu2f(r.z),acc[2]); acc[3]=fmaf(wj,hu2f(r.w),acc[3]);
        }
      }
    }
  }

  // ---- bias + LayerNorm + ReLU (wave-level) ----
  float vals[CPL];
  float ls=0.f;
#pragma unroll
  for (int c=0;c<CPL;c+=4){
    float4 b4 = *(const float4*)(bias + c0 + c);
    vals[c]=acc[c]+b4.x; vals[c+1]=acc[c+1]+b4.y; vals[c+2]=acc[c+2]+b4.z; vals[c+3]=acc[c+3]+b4.w;
    ls += vals[c]+vals[c+1]+vals[c+2]+vals[c+3];
  }
  float mu = wsum_all(ls) * (1.f/OUT);
  float lv=0.f;
#pragma unroll
  for (int c=0;c<CPL;c++){ float d=vals[c]-mu; lv += d*d; }
  float inv = rsqrtf(wsum_all(lv)*(1.f/OUT) + 1e-5f);

  if (outb){
    if constexpr (CPL==16){
#pragma unroll
      for (int c=0;c<CPL;c+=8){
        u16x8 o;
#pragma unroll
        for (int k=0;k<8;k++){
          float g = ln_g[c0+c+k], b = ln_b[c0+c+k];
          o[k] = f2hu(fmaxf((vals[c+k]-mu)*inv*g + b, 0.f));
        }
        *(u16x8*)(outb + (size_t)i*OUT + c0 + c) = o;
      }
    } else {
      ushort4 o;
      o.x = f2hu(fmaxf((vals[0]-mu)*inv*ln_g[c0+0] + ln_b[c0+0], 0.f));
      o.y = f2hu(fmaxf((vals[1]-mu)*inv*ln_g[c0+1] + ln_b[c0+1], 0.f));
      o.z = f2hu(fmaxf((vals[2]-mu)*inv*ln_g[c0+2] + ln_b[c0+2], 0.f));
      o.w = f2hu(fmaxf((vals[3]-mu)*inv*ln_g[c0+3] + ln_b[c0+3], 0.f));
      *(ushort4*)(outb + (size_t)i*OUT + c0) = o;
    }
  } else {
#pragma unroll
    for (int c=0;c<CPL;c+=4){
      float4 g4 = *(const float4*)(ln_g + c0 + c);
      float4 b4 = *(const float4*)(ln_b + c0 + c);
      float4 o;
      o.x = fmaxf((vals[c+0]-mu)*inv*g4.x + b4.x, 0.f);
      o.y = fmaxf((vals[c+1]-mu)*inv*g4.y + b4.y, 0.f);
      o.z = fmaxf((vals[c+2]-mu)*inv*g4.z + b4.z, 0.f);
      o.w = fmaxf((vals[c+3]-mu)*inv*g4.w + b4.w, 0.f);
      *(float4*)(outf + (size_t)i*OUT + c0 + c) = o;
    }
  }
}

// ---------------- mean pool + classifier ----------------
__global__ void colsum_kernel(const float* __restrict__ h2, float* __restrict__ gsum, int n){
  int c = threadIdx.x; // 256
  float acc=0;
  for (int i=blockIdx.x;i<n;i+=gridDim.x) acc += h2[(size_t)i*256 + c];
  atomicAdd(&gsum[c], acc);
}

__launch_bounds__(128)
__global__ void cls_kernel(const float* __restrict__ gsum,
                           const float* __restrict__ w1, const float* __restrict__ b1,
                           const float* __restrict__ w2, const float* __restrict__ b2,
                           float* __restrict__ outp){
  __shared__ float g[256];
  __shared__ float hid[128];
  int t = threadIdx.x;
  g[t]     = gsum[t]    *(1.f/N_NODES);
  g[t+128] = gsum[t+128]*(1.f/N_NODES);
  __syncthreads();
  float a = b1[t];
  for (int c=0;c<256;c++) a = fmaf(g[c], w1[c*128+t], a);
  hid[t] = fmaxf(a, 0.f);
  __syncthreads();
  if (t<2){
    float o = b2[t];
    for (int j=0;j<128;j++) o = fmaf(hid[j], w2[j*2+t], o);
    outp[t] = o;
  }
}

// ---------------- launch ----------------
extern "C" void kernel_launch(void* const* d_in, const int* in_sizes, int n_in,
                              void* d_out, int out_size, void* d_ws, size_t ws_size,
                              hipStream_t stream)
{
  const float* x      = (const float*)d_in[0];
  const int*   ei     = (const int*)  d_in[1];
  const float* ea     = (const float*)d_in[2];
  const float* ca_qw  = (const float*)d_in[3];
  const float* ca_kw  = (const float*)d_in[5];
  const float* ca_kb  = (const float*)d_in[6];
  const float* ca_vw  = (const float*)d_in[7];
  const float* ca_vb  = (const float*)d_in[8];
  const float* ca_ow  = (const float*)d_in[9];
  const float* ca_ob  = (const float*)d_in[10];
  const float* g0_w   = (const float*)d_in[11];
  const float* g0_ew  = (const float*)d_in[12];
  const float* g0_as  = (const float*)d_in[13];
  const float* g0_ad  = (const float*)d_in[14];
  const float* g0_ae  = (const float*)d_in[15];
  const float* g0_b   = (const float*)d_in[16];
  const float* ln0_g  = (const float*)d_in[17];
  const float* ln0_b  = (const float*)d_in[18];
  const float* g1_w   = (const float*)d_in[19];
  const float* g1_ew  = (const float*)d_in[20];
  const float* g1_as  = (const float*)d_in[21];
  const float* g1_ad  = (const float*)d_in[22];
  const float* g1_ae  = (const float*)d_in[23];
  const float* g1_b   = (const float*)d_in[24];
  const float* ln1_g  = (const float*)d_in[25];
  const float* ln1_b  = (const float*)d_in[26];
  const float* g2_w   = (const float*)d_in[27];
  const float* g2_ew  = (const float*)d_in[28];
  const float* g2_as  = (const float*)d_in[29];
  const float* g2_ad  = (const float*)d_in[30];
  const float* g2_ae  = (const float*)d_in[31];
  const float* g2_b   = (const float*)d_in[32];
  const float* ln2_g  = (const float*)d_in[33];
  const float* ln2_b  = (const float*)d_in[34];
  const float* cls_w1 = (const float*)d_in[35];
  const float* cls_b1 = (const float*)d_in[36];
  const float* cls_w2 = (const float*)d_in[37];
  const float* cls_b2 = (const float*)d_in[38];
  float* outp = (float*)d_out;

  const int N = N_NODES, E = N_EDGES;

  char* base = (char*)d_ws;
  size_t o = 0;
  auto alloc = [&](size_t bytes)->void*{
    void* p = base + o;
    o += (bytes + 255) & ~(size_t)255;
    return p;
  };
  unsigned short* hF   = (unsigned short*)alloc((size_t)N*1024*2); // GEMM output h (f16)
  unsigned short* Af   = (unsigned short*)alloc((size_t)N*1280*2); // f16 activations (x, then agg out)
  float*          h2   = (float*)         alloc((size_t)N*256*4);  // layer-2 agg out (f32)
  unsigned short* Wt   = (unsigned short*)alloc((size_t)1280*1024*2);
  float* alsp      = (float*)alloc((size_t)8*N*4);    // per-tile partials
  float* aldp      = (float*)alloc((size_t)8*N*4);
  float* als       = (float*)alloc((size_t)2*N*4*4);  // als | ald contiguous
  float* ald       = als + (size_t)N*4;
  float* scores    = (float*)alloc((size_t)N*4);
  float* wts       = (float*)alloc((size_t)N*4);
  int*   cnt       = (int*)  alloc((size_t)N*4);
  float* easum     = (float*)alloc((size_t)N*4);
  int*   off       = (int*)  alloc((size_t)(N+1)*4);
  int*   fill      = (int*)  alloc((size_t)N*4);
  int*   csr_src   = (int*)  alloc((size_t)E*4);
  float* csr_ea    = (float*)alloc((size_t)E*4);
  float* loop_attr = (float*)alloc((size_t)N*4);
  float* Kv        = (float*)alloc(256*4);
  float* Vv        = (float*)alloc(256*4);
  float* qK        = (float*)alloc(1280*4);
  float* Vo        = (float*)alloc(1280*4);
  float* obW       = (float*)alloc(1024*4);
  float* VoW       = (float*)alloc(1024*4);
  float* web       = (float*)alloc(16*4);
  float* gsum      = (float*)alloc(256*4);

  hipMemsetAsync(cnt,   0, (size_t)N*4, stream);
  hipMemsetAsync(easum, 0, (size_t)N*4, stream);
  hipMemsetAsync(fill,  0, (size_t)N*4, stream);
  hipMemsetAsync(gsum,  0, 256*4,       stream);
  hipMemsetAsync(obW,   0, 1024*4,      stream);
  hipMemsetAsync(VoW,   0, 1024*4,      stream);

  // ---- edge preprocessing (CSR by dst) ----
  int eblocks = (E + 255)/256;
  edge_count_kernel<<<eblocks,256,0,stream>>>(ei, ea, cnt, easum, E);
  scan_kernel<<<1,1024,0,stream>>>(cnt, easum, off, loop_attr, N);
  edge_fill_kernel<<<eblocks,256,0,stream>>>(ei, ea, off, fill, csr_src, csr_ea, E);

  // ---- cross-attention, rank-1 collapsed ----
  kv_kernel<<<1,256,0,stream>>>(x, ca_kw, ca_kb, ca_vw, ca_vb, Kv, Vv);
  qkvo_kernel<<<25,256,0,stream>>>(ca_qw, ca_ow, Kv, Vv, qK, Vo);
  xh_scores_kernel<<<(N+3)/4,256,0,stream>>>(x, qK, Af, scores, N);
  obw_kernel<<<dim3(4,10),256,0,stream>>>(ca_ob, Vo, g0_w, obW, VoW);
  softmax_nodes<<<1,1024,0,stream>>>(scores, wts, N);

  const int mTiles  = (N + 127)/128;      // 157
  const int mGroups = (mTiles + 7)/8;     // 20
  const int NB4 = (N + 3)/4;              // wave-per-node blocks

  // ---- layer 0 ----
  wt_f16_kernel<<<dim3(1280/32, 1024/32),256,0,stream>>>(g0_w, 1280, 1024, Wt);
  gemm_f16<<<dim3(8, mGroups*8),256,0,stream>>>(Af, Wt, hF, N, 1024, 1280, obW, VoW, wts,
                                                g0_as, g0_ad, alsp, aldp);
  als_combine<<<(N*4+255)/256,256,0,stream>>>(alsp, aldp, als, ald, N, 4, g0_ew, g0_ae, web);
  gat_agg_ln_wave<4><<<NB4,256,0,stream>>>(hF, als, ald, off, csr_src, csr_ea, loop_attr,
                                           web, g0_b, ln0_g, ln0_b, nullptr, Af, N);

  // ---- layer 1 ----
  wt_f16_kernel<<<dim3(1024/32, 1024/32),256,0,stream>>>(g1_w, 1024, 1024, Wt);
  gemm_f16<<<dim3(8, mGroups*8),256,0,stream>>>(Af, Wt, hF, N, 1024, 1024, nullptr, nullptr, nullptr,
                                                g1_as, g1_ad, alsp, aldp);
  als_combine<<<(N*4+255)/256,256,0,stream>>>(alsp, aldp, als, ald, N, 4, g1_ew, g1_ae, web);
  gat_agg_ln_wave<4><<<NB4,256,0,stream>>>(hF, als, ald, off, csr_src, csr_ea, loop_attr,
                                           web, g1_b, ln1_g, ln1_b, nullptr, Af, N);

  // ---- layer 2 (1 head, 256 out) ----
  wt_f16_kernel<<<dim3(1024/32, 256/32),256,0,stream>>>(g2_w, 1024, 256, Wt);
  gemm_f16<<<dim3(8, mGroups*2),256,0,stream>>>(Af, Wt, hF, N, 256, 1024, nullptr, nullptr, nullptr,
                                                g2_as, g2_ad, alsp, aldp);
  als_combine<<<(N+255)/256,256,0,stream>>>(alsp, aldp, als, ald, N, 1, g2_ew, g2_ae, web);
  gat_agg_ln_wave<1><<<NB4,256,0,stream>>>(hF, als, ald, off, csr_src, csr_ea, loop_attr,
                                           web, g2_b, ln2_g, ln2_b, h2, nullptr, N);

  // ---- mean pool + classifier ----
  colsum_kernel<<<256,256,0,stream>>>(h2, gsum, N);
  cls_kernel<<<1,128,0,stream>>>(gsum, cls_w1, cls_b1, cls_w2, cls_b2, outp);

  (void)in_sizes; (void)n_in; (void)out_size; (void)ws_size;
}